// Round 6
// baseline (441.559 us; speedup 1.0000x reference)
//
#include <hip/hip_runtime.h>
#include <hip/hip_fp16.h>
#include <cstdint>
#include <cstddef>

#define NB    8192
#define DD    768
#define NE    16
#define EDD   1536
#define KTOP  100
#define MAXT  8192
#define CAND_MAX 256
#define K1BLK 2048
#define NSTEP 12
#define BKBYTES 128      // 64 k * 2B
#define CONF_ULP 21
#define BAND_ULP 20

typedef __attribute__((ext_vector_type(4))) float f32x4;
typedef __attribute__((ext_vector_type(8))) short bf16x8;

#define VMCNT8() asm volatile("s_waitcnt vmcnt(8)" ::: "memory")
#define VMCNT4() asm volatile("s_waitcnt vmcnt(4)" ::: "memory")
#define VMCNT0() asm volatile("s_waitcnt vmcnt(0)" ::: "memory")

__device__ __forceinline__ unsigned short f2bf(float v) {
    unsigned int u = __float_as_uint(v);
    u += 0x7FFFu + ((u >> 16) & 1u);   // RNE to bf16
    return (unsigned short)(u >> 16);
}
__device__ __forceinline__ float bf2f(unsigned short h) {
    return __uint_as_float(((unsigned int)h) << 16);
}
__device__ __forceinline__ unsigned short f2h_bits(float v) {
    return __half_as_ushort(__float2half(v));
}
__device__ __forceinline__ float h2f_bits(unsigned short b) {
    return __half2float(__ushort_as_half(b));
}
__device__ __forceinline__ void async16(const void* g, void* l) {
    __builtin_amdgcn_global_load_lds(
        (const __attribute__((address_space(1))) unsigned int*)g,
        (__attribute__((address_space(3))) unsigned int*)l, 16, 0, 0);
}

// ---------------------------------------------------------------- K0: converts
__global__ __launch_bounds__(256) void k0_prep_x(
    const float* __restrict__ x, const float* __restrict__ b_dec,
    unsigned short* __restrict__ xbf)
{
    const int i = blockIdx.x * 256 + threadIdx.x;      // over 1,572,864 float4s
    const float4 v = reinterpret_cast<const float4*>(x)[i];
    const float4 bd = reinterpret_cast<const float4*>(b_dec)[i % (DD / 4)];
    ushort4 h;
    h.x = f2bf(v.x - bd.x); h.y = f2bf(v.y - bd.y);
    h.z = f2bf(v.z - bd.z); h.w = f2bf(v.w - bd.w);
    reinterpret_cast<ushort4*>(xbf)[i] = h;
}

__global__ __launch_bounds__(256) void k0_cvt_bf(
    const float* __restrict__ src, unsigned short* __restrict__ dst)
{
    const int i = blockIdx.x * 256 + threadIdx.x;
    const float4 v = reinterpret_cast<const float4*>(src)[i];
    ushort4 h;
    h.x = f2bf(v.x); h.y = f2bf(v.y); h.z = f2bf(v.z); h.w = f2bf(v.w);
    reinterpret_cast<ushort4*>(dst)[i] = h;
}

// ---------------------------------------------------------------- K1a: gate
__global__ __launch_bounds__(256) void k1_gate(
    const float* __restrict__ x, const float* __restrict__ gate_W,
    const float* __restrict__ gate_b, const float* __restrict__ b_gate,
    int* __restrict__ eids, double* __restrict__ entw,
    int* __restrict__ rnk, int* __restrict__ blk_cnt,
    int* __restrict__ rnk0, int* __restrict__ blk_cnt0)
{
    __shared__ int cnt[NE];
    __shared__ int cnt0[NE];
    const int wid  = threadIdx.x >> 6;
    const int lane = threadIdx.x & 63;
    const int blk  = blockIdx.x;
    const int tok  = blk * 4 + wid;

    if (threadIdx.x < NE) { cnt[threadIdx.x] = 0; cnt0[threadIdx.x] = 0; }
    __syncthreads();

    double xv[12];
#pragma unroll
    for (int j = 0; j < 12; ++j) {
        const int k = j * 64 + lane;
        xv[j] = (double)x[(size_t)tok * DD + k] - (double)b_gate[k];
    }

    double myLogit = -1.0e300;
    for (int e = 0; e < NE; ++e) {
        double d = 0.0;
#pragma unroll
        for (int j = 0; j < 12; ++j)
            d += xv[j] * (double)gate_W[e * DD + j * 64 + lane];
#pragma unroll
        for (int off = 32; off > 0; off >>= 1)
            d += __shfl_xor(d, off);
        if (lane == e) myLogit = d + (double)gate_b[e];
    }

    double m = myLogit;
#pragma unroll
    for (int off = 8; off > 0; off >>= 1) {
        double o = __shfl_xor(m, off); m = (o > m) ? o : m;
    }
    double p = exp(myLogit - m);
    double ssum = p;
#pragma unroll
    for (int off = 8; off > 0; off >>= 1) ssum += __shfl_xor(ssum, off);
    const double score = p / ssum;

    const bool lt16 = (lane < NE);
    double m1 = score;
#pragma unroll
    for (int off = 8; off > 0; off >>= 1) {
        double o = __shfl_xor(m1, off); m1 = (o > m1) ? o : m1;
    }
    unsigned long long b0 = __ballot(lt16 && (score == m1));
    const int i0 = __ffsll(b0) - 1;
    double sc2 = (lane == i0) ? -1.0 : score;
    double m2 = sc2;
#pragma unroll
    for (int off = 8; off > 0; off >>= 1) {
        double o = __shfl_xor(m2, off); m2 = (o > m2) ? o : m2;
    }
    unsigned long long b1 = __ballot(lt16 && (sc2 == m2));
    const int i1 = __ffsll(b1) - 1;

    if (lane == 0) {
        const double w0 = 1.0 / (1.0 + exp(m2 - m1));
        const double w1 = 1.0 - w0;
        eids[tok * 2 + 0] = i0;
        eids[tok * 2 + 1] = i1;
        entw[tok * 2 + 0] = w0;
        entw[tok * 2 + 1] = w1;
        rnk[tok * 2 + 0] = atomicAdd(&cnt[i0], 1);
        rnk[tok * 2 + 1] = atomicAdd(&cnt[i1], 1);
        rnk0[tok] = atomicAdd(&cnt0[i0], 1);
    }
    __syncthreads();
    if (threadIdx.x < NE) {
        blk_cnt [threadIdx.x * K1BLK + blk] = cnt [threadIdx.x];
        blk_cnt0[threadIdx.x * K1BLK + blk] = cnt0[threadIdx.x];
    }
}

// ------------------------------------------- K1b: scan (32 blocks: 16 entry-lists, 16 slot0-order)
__global__ __launch_bounds__(256) void k1_scan(
    const int* __restrict__ bc,  int* __restrict__ bo,  int* __restrict__ counts,
    const int* __restrict__ bc0, int* __restrict__ bo0, int* __restrict__ counts0)
{
    __shared__ int tsum[256];
    const int g = blockIdx.x;
    const int e = g & 15;
    const int* src = (g >= NE) ? bc0 : bc;
    int* dst       = (g >= NE) ? bo0 : bo;
    int* cn        = (g >= NE) ? counts0 : counts;
    const int t = threadIdx.x;
    int loc[8]; int s = 0;
#pragma unroll
    for (int i = 0; i < 8; ++i) { loc[i] = s; s += src[e * K1BLK + t * 8 + i]; }
    tsum[t] = s;
    __syncthreads();
    for (int off = 1; off < 256; off <<= 1) {
        const int u = (t >= off) ? tsum[t - off] : 0;
        __syncthreads();
        tsum[t] += u;
        __syncthreads();
    }
    const int excl = tsum[t] - s;
#pragma unroll
    for (int i = 0; i < 8; ++i) dst[e * K1BLK + t * 8 + i] = excl + loc[i];
    if (t == 255) cn[e] = tsum[255];
}

// ---------------------------------------------------------------- K1c: scatter
__global__ __launch_bounds__(256) void k1_scatter(
    const int* __restrict__ eids, const int* __restrict__ rnk,
    const int* __restrict__ blk_off, int* __restrict__ lists,
    const int* __restrict__ rnk0, const int* __restrict__ blk_off0,
    const int* __restrict__ counts0, int* __restrict__ tokord)
{
    const int i = blockIdx.x * 256 + threadIdx.x;   // 16384 entries
    const int e = eids[i];
    const int blk = i >> 3;
    lists[e * MAXT + blk_off[e * K1BLK + blk] + rnk[i]] = i;
    if (!(i & 1)) {
        const int tok = i >> 1;
        int base0 = 0;
#pragma unroll
        for (int e2 = 0; e2 < NE; ++e2) base0 += (e2 < e) ? counts0[e2] : 0;
        tokord[base0 + blk_off0[e * K1BLK + blk] + rnk0[tok]] = tok;
    }
}

// ------------------------------------------------- K2: grouped expert GEMM
// pure-bf16, double-buffered LDS, all-async staging, counted vmcnt (T3+T4).
template<bool WBF>
__global__ __launch_bounds__(256, 2) void k2_encode(
    const unsigned short* __restrict__ xbf,
    const unsigned short* __restrict__ wbf,
    const float* __restrict__ expert_W,
    const float* __restrict__ expert_b,
    const int* __restrict__ counts, const int* __restrict__ lists,
    const double* __restrict__ entw, unsigned short* __restrict__ fbuf)
{
    const int e = blockIdx.z;
    const int cnt = counts[e];
    const int mbase = blockIdx.y * 128;
    if (mbase >= cnt) return;
    const int rows = min(128, cnt - mbase);
    const int nbase = blockIdx.x * 128;

    __shared__ char smem[65536];   // 2 buffers x (A 16KB | B 16KB)

    const int t = threadIdx.x;
    const int lane = t & 63;
    const int wid = t >> 6;
    const int wm = wid >> 1, wn = wid & 1;
    const int l15 = lane & 15, q = lane >> 4;
    const int rl = lane >> 3;          // row-within-8 for async staging
    const int cg = lane & 7;           // 16B chunk index
    const int xorc = (cg ^ rl) << 4;   // inverse-swizzled source chunk byte

    size_t asrc[4];
#pragma unroll
    for (int j = 0; j < 4; ++j) {
        const int r = (wid * 4 + j) * 8 + rl;
        const int rr = (r < rows) ? r : 0;
        const int tok = lists[e * MAXT + mbase + rr] >> 1;
        asrc[j] = (size_t)tok * (DD * 2) + xorc;
    }
    size_t bsrc[4];
#pragma unroll
    for (int j = 0; j < 4; ++j) {
        const int r = (wid * 4 + j) * 8 + rl;
        bsrc[j] = ((size_t)(e * EDD + nbase + r)) * (DD * 2) + xorc;
    }
    const int kq = t & 15, rg = t >> 4;   // !WBF B-convert map

    f32x4 acc[4][4];
#pragma unroll
    for (int a = 0; a < 4; ++a)
#pragma unroll
        for (int b = 0; b < 4; ++b)
            acc[a][b] = f32x4{0.f, 0.f, 0.f, 0.f};

    auto stageA = [&](int s, char* buf) {
#pragma unroll
        for (int j = 0; j < 4; ++j)
            async16((const char*)xbf + asrc[j] + (size_t)s * BKBYTES,
                    buf + ((wid * 4 + j) << 10));
    };
    auto stageB_async = [&](int s, char* buf) {
#pragma unroll
        for (int j = 0; j < 4; ++j)
            async16((const char*)wbf + bsrc[j] + (size_t)s * BKBYTES,
                    buf + 16384 + ((wid * 4 + j) << 10));
    };
    auto stageB_cvt = [&](int s, char* buf) {
#pragma unroll
        for (int j = 0; j < 8; ++j) {
            const int r = rg * 8 + j;
            const float4 bv = *reinterpret_cast<const float4*>(
                expert_W + ((size_t)e * EDD + nbase + r) * DD + s * 64 + kq * 4);
            ushort4 b4;
            b4.x = f2bf(bv.x); b4.y = f2bf(bv.y); b4.z = f2bf(bv.z); b4.w = f2bf(bv.w);
            *reinterpret_cast<ushort4*>(
                buf + 16384 + ((r * 128 + kq * 8) ^ ((r & 7) << 4))) = b4;
        }
    };
    auto compute = [&](char* buf) {
#pragma unroll
        for (int ks = 0; ks < 2; ++ks) {
            bf16x8 ah[4], bh[4];
#pragma unroll
            for (int fm = 0; fm < 4; ++fm) {
                const int row = wm * 64 + fm * 16 + l15;
                ah[fm] = *reinterpret_cast<const bf16x8*>(
                    buf + row * 128 + ((ks * 64 + q * 16) ^ ((row & 7) << 4)));
            }
#pragma unroll
            for (int fn = 0; fn < 4; ++fn) {
                const int row = wn * 64 + fn * 16 + l15;
                bh[fn] = *reinterpret_cast<const bf16x8*>(
                    buf + 16384 + row * 128 + ((ks * 64 + q * 16) ^ ((row & 7) << 4)));
            }
#pragma unroll
            for (int fm = 0; fm < 4; ++fm)
#pragma unroll
                for (int fn = 0; fn < 4; ++fn)
                    acc[fm][fn] = __builtin_amdgcn_mfma_f32_16x16x32_bf16(
                        ah[fm], bh[fn], acc[fm][fn], 0, 0, 0);
        }
    };

    // prologue: stage tile 0 into buffer 0
    if constexpr (WBF) {
        stageA(0, smem);
        stageB_async(0, smem);
    } else {
        stageB_cvt(0, smem);
        stageA(0, smem);
    }

    for (int s = 0; s < NSTEP; ++s) {
        char* cur = smem + ((s & 1) << 15);
        char* nxt = smem + (((s & 1) ^ 1) << 15);
        if (s + 1 < NSTEP) {
            if constexpr (WBF) {
                stageA(s + 1, nxt);
                stageB_async(s + 1, nxt);
                VMCNT8();              // retire tile s, keep tile s+1 in flight
            } else {
                stageB_cvt(s + 1, nxt);
                stageA(s + 1, nxt);
                VMCNT4();
            }
        } else {
            VMCNT0();
        }
        __syncthreads();
        compute(cur);
        __syncthreads();
    }

    // epilogue: C/D layout col=lane&15, row=(lane>>4)*4+reg; bias+relu+renorm; f16 out
#pragma unroll
    for (int fm = 0; fm < 4; ++fm) {
#pragma unroll
        for (int r = 0; r < 4; ++r) {
            const int ml = wm * 64 + fm * 16 + q * 4 + r;
            if (ml >= rows) continue;
            const int ent = lists[e * MAXT + mbase + ml];
            const float ren = (float)entw[ent];
            unsigned short* fout = fbuf + (size_t)ent * EDD + nbase;
#pragma unroll
            for (int fn = 0; fn < 4; ++fn) {
                const int nl = wn * 64 + fn * 16 + l15;
                float v = acc[fm][fn][r] + expert_b[e * EDD + nbase + nl];
                v = fmaxf(v, 0.f) * ren;
                fout[nl] = f2h_bits(v);
            }
        }
    }
}

// --------------------------- K3: per-token exact top-100 + fused decode
// expert-major token order + XCD-chunked dispatch; 2-rows-per-step decode
// with 16B gathers (latency x MLP fix).
template<int DEC16>
__global__ __launch_bounds__(256) void k3_topk_decode(
    const float* __restrict__ x, const float* __restrict__ b_dec,
    const float* __restrict__ expert_W, const float* __restrict__ expert_b,
    const int* __restrict__ eids, const double* __restrict__ entw,
    const unsigned short* __restrict__ fbuf,
    const float* __restrict__ decoder, const unsigned short* __restrict__ dec16,
    const int* __restrict__ tokord, float* __restrict__ out)
{
    // XCD-chunked: each of 8 XCDs walks a contiguous 1024-token slice of the
    // expert-major order, so its L2 holds ~2 expert dict slices.
    const int bid = blockIdx.x;
    const int tok = tokord[(bid & 7) * (NB / 8) + (bid >> 3)];
    const int t = threadIdx.x;

    // arena overlay: [fv 6144 | hist 1024 | cidx 1024 | cval 2048] before decode;
    // red[4*768 floats = 12288] after selection (fv/hist/cidx/cval all dead then).
    __shared__ __align__(16) char arena[12288];
    unsigned short* fv   = (unsigned short*)arena;
    unsigned int*   hist = (unsigned int*)(arena + 6144);
    int*            cidx = (int*)(arena + 7168);
    double*         cval = (double*)(arena + 8192);
    float*          red  = (float*)arena;
    __shared__ int hb_s, T_s, rem_s, tz_s, nsel_s, ncand_s, total_s, need_s;
    __shared__ int   sel_didx[KTOP];
    __shared__ float sel_act[KTOP];

    const unsigned int* frow = reinterpret_cast<const unsigned int*>(fbuf + (size_t)tok * 2 * EDD);
#pragma unroll
    for (int i = 0; i < 6; ++i)
        reinterpret_cast<unsigned int*>(fv)[t + 256 * i] = frow[t + 256 * i];
    if (t == 0) { tz_s = 0; nsel_s = 0; ncand_s = 0; }
    hist[t] = 0u;
    __syncthreads();

    // pass 1: top byte of f16 bits (all values >= 0)
#pragma unroll
    for (int i = 0; i < 12; ++i) {
        const unsigned int u = fv[t + 256 * i];
        if (u) atomicAdd(&hist[u >> 8], 1u);
    }
    __syncthreads();
    if (t == 0) {
        unsigned int cum = 0; int v = 255;
        for (; v >= 0; --v) { const unsigned int c = hist[v]; if (cum + c >= KTOP) break; cum += c; }
        if (v < 0) tz_s = 1;
        else { hb_s = v; rem_s = KTOP - (int)cum; }
    }
    __syncthreads();

    if (!tz_s) {
        hist[t] = 0u;
        __syncthreads();
        const unsigned int hb = (unsigned int)hb_s;
#pragma unroll
        for (int i = 0; i < 12; ++i) {
            const unsigned int u = fv[t + 256 * i];
            if (u && (u >> 8) == hb) atomicAdd(&hist[u & 255u], 1u);
        }
        __syncthreads();
        if (t == 0) {
            const int rem = rem_s; unsigned int cum = 0; int v = 255;
            for (; v >= 0; --v) { const unsigned int c = hist[v]; if (cum + c >= (unsigned int)rem) break; cum += c; }
            T_s = (hb_s << 8) | v;
        }
        __syncthreads();
    }

    if (tz_s) {
        // fewer than 100 positives: take them all (rest are exact zeros)
#pragma unroll
        for (int i = 0; i < 12; ++i) {
            const int j = t + 256 * i;
            const unsigned int u = fv[j];
            if (u) {
                const int p = atomicAdd(&nsel_s, 1);
                const int slot = (j >= EDD) ? 1 : 0;
                const int n = j - slot * EDD;
                sel_didx[p] = eids[tok * 2 + slot] * EDD + n;
                sel_act[p] = h2f_bits((unsigned short)u);
            }
        }
        __syncthreads();
        if (t == 0) total_s = nsel_s;
        __syncthreads();
    } else {
        const int T = T_s;
#pragma unroll
        for (int i = 0; i < 12; ++i) {
            const int j = t + 256 * i;
            const unsigned int u = fv[j];
            if ((int)u >= T + CONF_ULP) {
                const int p = atomicAdd(&nsel_s, 1);
                const int slot = (j >= EDD) ? 1 : 0;
                const int n = j - slot * EDD;
                sel_didx[p] = eids[tok * 2 + slot] * EDD + n;
                sel_act[p] = h2f_bits((unsigned short)u);
            } else if (u != 0u && (int)u + BAND_ULP >= T) {
                const int c = atomicAdd(&ncand_s, 1);
                if (c < CAND_MAX) cidx[c] = j;
            }
        }
        __syncthreads();

        // fp64 re-evaluation of candidates, one wave per candidate
        {
            const int ncand = min(ncand_s, CAND_MAX);
            const int wv = t >> 6, lane = t & 63;
            for (int c = wv; c < ncand; c += 4) {
                const int j = cidx[c];
                const int slot = (j >= EDD) ? 1 : 0;
                const int n = j - slot * EDD;
                const int ee = eids[tok * 2 + slot];
                const float* wr = expert_W + ((size_t)ee * EDD + n) * DD;
                const float* xr = x + (size_t)tok * DD;
                double d = 0.0;
#pragma unroll
                for (int jj = 0; jj < 12; ++jj) {
                    const int k = jj * 64 + lane;
                    d += ((double)xr[k] - (double)b_dec[k]) * (double)wr[k];
                }
#pragma unroll
                for (int off = 32; off > 0; off >>= 1) d += __shfl_xor(d, off);
                if (lane == 0) {
                    double z = d + (double)expert_b[ee * EDD + n];
                    if (z < 0.0) z = 0.0;
                    cval[c] = z * entw[tok * 2 + slot];
                }
            }
        }
        __syncthreads();
        if (t == 0) {
            const int ncand = min(ncand_s, CAND_MAX);
            int need = KTOP - nsel_s;
            if (need > ncand) need = ncand;
            if (need < 0) need = 0;
            need_s = need;
            total_s = nsel_s + need;
        }
        __syncthreads();

        // parallel rank-based selection among candidates (value desc, dict idx asc)
        {
            const int ncand = min(ncand_s, CAND_MAX);
            if (t < ncand) {
                const int j = cidx[t];
                const int slot = (j >= EDD) ? 1 : 0;
                const int my_didx = eids[tok * 2 + slot] * EDD + (j - slot * EDD);
                const double v = cval[t];
                int rank = 0;
                for (int i = 0; i < ncand; ++i) {
                    const int ji = cidx[i];
                    const int si = (ji >= EDD) ? 1 : 0;
                    const int di = eids[tok * 2 + si] * EDD + (ji - si * EDD);
                    const double vi = cval[i];
                    rank += (vi > v) || (vi == v && di < my_didx);
                }
                if (rank < need_s) {
                    sel_didx[nsel_s + rank] = my_didx;
                    sel_act[nsel_s + rank] = (float)v;
                }
            }
        }
        __syncthreads();
    }

    // fused decode. DEC16: 2 rows per wave-step (half-wave each), 16B loads,
    // 48B/lane/row, 24 accumulators, shfl_xor(32) cross-half reduce.
    const int total = total_s;
    const int wv = t >> 6;
    const int lane = t & 63;

    if (DEC16) {
        const int half = lane >> 5;          // 0: row k, 1: row k+1
        const int l32 = lane & 31;
        float accd[24];
#pragma unroll
        for (int i = 0; i < 24; ++i) accd[i] = 0.f;

        auto body = [&](int jb) {
            const int k0 = jb + half;
            const int kk = (k0 < total) ? k0 : 0;
            const float a = (k0 < total) ? sel_act[k0] : 0.f;
            const char* dr = (const char*)(dec16 + (size_t)sel_didx[kk] * DD) + l32 * 48;
            const uint4 u0 = *reinterpret_cast<const uint4*>(dr);
            const uint4 u1 = *reinterpret_cast<const uint4*>(dr + 16);
            const uint4 u2 = *reinterpret_cast<const uint4*>(dr + 32);
            auto acc2 = [&](unsigned int u, int i) {
                accd[i]     += a * __uint_as_float(u << 16);
                accd[i + 1] += a * __uint_as_float(u & 0xffff0000u);
            };
            acc2(u0.x, 0);  acc2(u0.y, 2);  acc2(u0.z, 4);  acc2(u0.w, 6);
            acc2(u1.x, 8);  acc2(u1.y, 10); acc2(u1.z, 12); acc2(u1.w, 14);
            acc2(u2.x, 16); acc2(u2.y, 18); acc2(u2.z, 20); acc2(u2.w, 22);
        };
        {
            int jb = wv * 2;
            for (; jb + 8 < total; jb += 16) { body(jb); body(jb + 8); }
            if (jb < total) body(jb);
        }
#pragma unroll
        for (int i = 0; i < 24; ++i) accd[i] += __shfl_xor(accd[i], 32);
        if (lane < 32) {
#pragma unroll
            for (int i = 0; i < 24; ++i)
                red[wv * DD + l32 * 24 + i] = accd[i];
        }
        __syncthreads();
    } else {
        float accd[12];
#pragma unroll
        for (int i = 0; i < 12; ++i) accd[i] = 0.f;
        auto body = [&](int k) {
            const float a = sel_act[k];
            const float* dr = decoder + (size_t)sel_didx[k] * DD + lane * 12;
            const float4 f0 = *reinterpret_cast<const float4*>(dr);
            const float4 f1 = *reinterpret_cast<const float4*>(dr + 4);
            const float4 f2 = *reinterpret_cast<const float4*>(dr + 8);
            accd[0] += a * f0.x;  accd[1]  += a * f0.y;
            accd[2] += a * f0.z;  accd[3]  += a * f0.w;
            accd[4] += a * f1.x;  accd[5]  += a * f1.y;
            accd[6] += a * f1.z;  accd[7]  += a * f1.w;
            accd[8] += a * f2.x;  accd[9]  += a * f2.y;
            accd[10] += a * f2.z; accd[11] += a * f2.w;
        };
        {
            int k = wv;
            for (; k + 4 < total; k += 8) { body(k); body(k + 4); }
            if (k < total) body(k);
        }
#pragma unroll
        for (int i = 0; i < 12; ++i)
            red[wv * DD + lane * 12 + i] = accd[i];
        __syncthreads();
    }

#pragma unroll
    for (int i = 0; i < 3; ++i) {
        const int j = t + 256 * i;
        out[(size_t)tok * DD + j] =
            red[j] + red[DD + j] + red[2 * DD + j] + red[3 * DD + j] + b_dec[j];
    }
}

// sentinel fill if workspace is too small (diagnosable: absmax ~ 12345)
__global__ void k_sentinel(float* __restrict__ out, int n) {
    int i = blockIdx.x * blockDim.x + threadIdx.x;
    if (i < n) out[i] = 12345.0f;
}

extern "C" void kernel_launch(void* const* d_in, const int* in_sizes, int n_in,
                              void* d_out, int out_size, void* d_ws, size_t ws_size,
                              hipStream_t stream)
{
    (void)in_sizes; (void)n_in;
    const float* x        = (const float*)d_in[0];
    const float* gate_W   = (const float*)d_in[1];
    const float* gate_b   = (const float*)d_in[2];
    const float* b_gate   = (const float*)d_in[3];
    const float* b_dec    = (const float*)d_in[4];
    const float* expert_W = (const float*)d_in[5];
    const float* expert_b = (const float*)d_in[6];
    const float* decoder  = (const float*)d_in[7];
    float* out = (float*)d_out;

    char* ws = (char*)d_ws;
    const size_t off_counts0 = 64;
    const size_t off_blkcnt = 256;
    const size_t off_blkoff = off_blkcnt + (size_t)NE * K1BLK * 4;
    const size_t off_rnk    = off_blkoff + (size_t)NE * K1BLK * 4;
    const size_t off_eids   = off_rnk    + (size_t)NB * 2 * 4;
    const size_t off_entw   = off_eids   + (size_t)NB * 2 * 4;
    const size_t off_lists  = off_entw   + (size_t)NB * 2 * 8;
    const size_t off_fbuf   = off_lists  + (size_t)NE * MAXT * 4;
    const size_t off_xbf    = off_fbuf   + (size_t)NB * 2 * EDD * 2;
    const size_t off_bc0    = off_xbf    + (size_t)NB * DD * 2;
    const size_t off_bo0    = off_bc0    + (size_t)NE * K1BLK * 4;
    const size_t off_rnk0   = off_bo0    + (size_t)NE * K1BLK * 4;
    const size_t off_tokord = off_rnk0   + (size_t)NB * 4;
    const size_t base_end   = off_tokord + (size_t)NB * 4;           // ~64.4 MB
    const size_t WSZ        = (size_t)NE * EDD * DD * 2;             // 37.75 MB

    if (ws_size < base_end) {
        k_sentinel<<<(out_size + 255) / 256, 256, 0, stream>>>(out, out_size);
        return;
    }
    size_t off = base_end;
    const bool have_w = (ws_size >= off + WSZ);
    unsigned short* wbf = have_w ? (unsigned short*)(ws + off) : nullptr;
    if (have_w) off += WSZ;
    const bool have_d = (ws_size >= off + WSZ);
    unsigned short* dec16v = have_d ? (unsigned short*)(ws + off) : nullptr;

    int*            counts  = (int*)ws;
    int*            counts0 = (int*)(ws + off_counts0);
    int*            blk_cnt = (int*)(ws + off_blkcnt);
    int*            blk_off = (int*)(ws + off_blkoff);
    int*            rnk     = (int*)(ws + off_rnk);
    int*            eids    = (int*)(ws + off_eids);
    double*         entw    = (double*)(ws + off_entw);
    int*            lists   = (int*)(ws + off_lists);
    unsigned short* fbuf    = (unsigned short*)(ws + off_fbuf);
    unsigned short* xbf     = (unsigned short*)(ws + off_xbf);
    int*            blk_cnt0= (int*)(ws + off_bc0);
    int*            blk_off0= (int*)(ws + off_bo0);
    int*            rnk0    = (int*)(ws + off_rnk0);
    int*            tokord  = (int*)(ws + off_tokord);

    hipMemsetAsync(counts, 0, 128, stream);

    k0_prep_x<<<(NB * DD / 4) / 256, 256, 0, stream>>>(x, b_dec, xbf);
    const int n4blocks = (NE * EDD * DD / 4) / 256;   // 18432
    if (have_w)
        k0_cvt_bf<<<n4blocks, 256, 0, stream>>>(expert_W, wbf);
    if (have_d)
        k0_cvt_bf<<<n4blocks, 256, 0, stream>>>(decoder, dec16v);

    k1_gate<<<K1BLK, 256, 0, stream>>>(x, gate_W, gate_b, b_gate, eids, entw,
                                       rnk, blk_cnt, rnk0, blk_cnt0);
    k1_scan<<<2 * NE, 256, 0, stream>>>(blk_cnt, blk_off, counts,
                                        blk_cnt0, blk_off0, counts0);
    k1_scatter<<<NB * 2 / 256, 256, 0, stream>>>(eids, rnk, blk_off, lists,
                                                 rnk0, blk_off0, counts0, tokord);

    dim3 g2(EDD / 128, MAXT / 128, NE);   // (ntile=12, mtile=64, e=16), early-exit
    if (have_w)
        k2_encode<true><<<g2, 256, 0, stream>>>(xbf, wbf, expert_W, expert_b,
                                                counts, lists, entw, fbuf);
    else
        k2_encode<false><<<g2, 256, 0, stream>>>(xbf, wbf, expert_W, expert_b,
                                                 counts, lists, entw, fbuf);

    if (have_d)
        k3_topk_decode<1><<<NB, 256, 0, stream>>>(x, b_dec, expert_W, expert_b, eids,
                                                  entw, fbuf, decoder, dec16v, tokord, out);
    else
        k3_topk_decode<0><<<NB, 256, 0, stream>>>(x, b_dec, expert_W, expert_b, eids,
                                                  entw, fbuf, decoder, dec16v, tokord, out);
}

// Round 7
// 410.000 us; speedup vs baseline: 1.0770x; 1.0770x over previous
//
#include <hip/hip_runtime.h>
#include <hip/hip_fp16.h>
#include <cstdint>
#include <cstddef>

#define NB    8192
#define DD    768
#define NE    16
#define EDD   1536
#define KTOP  100
#define MAXT  8192
#define CAND_MAX 256
#define K1BLK 2048
#define NSTEP 12
#define BKBYTES 128      // 64 k * 2B
#define CONF_ULP 21
#define BAND_ULP 20

typedef __attribute__((ext_vector_type(4))) float f32x4;
typedef __attribute__((ext_vector_type(8))) short bf16x8;

#define VMCNT8() asm volatile("s_waitcnt vmcnt(8)" ::: "memory")
#define VMCNT4() asm volatile("s_waitcnt vmcnt(4)" ::: "memory")
#define VMCNT0() asm volatile("s_waitcnt vmcnt(0)" ::: "memory")

__device__ __forceinline__ unsigned short f2bf(float v) {
    unsigned int u = __float_as_uint(v);
    u += 0x7FFFu + ((u >> 16) & 1u);   // RNE to bf16
    return (unsigned short)(u >> 16);
}
__device__ __forceinline__ float bf2f(unsigned short h) {
    return __uint_as_float(((unsigned int)h) << 16);
}
__device__ __forceinline__ unsigned short f2h_bits(float v) {
    return __half_as_ushort(__float2half(v));
}
__device__ __forceinline__ float h2f_bits(unsigned short b) {
    return __half2float(__ushort_as_half(b));
}
__device__ __forceinline__ void async16(const void* g, void* l) {
    __builtin_amdgcn_global_load_lds(
        (const __attribute__((address_space(1))) unsigned int*)g,
        (__attribute__((address_space(3))) unsigned int*)l, 16, 0, 0);
}

// ---------------------------------------------------------------- K0: converts
__global__ __launch_bounds__(256) void k0_prep_x(
    const float* __restrict__ x, const float* __restrict__ b_dec,
    unsigned short* __restrict__ xbf)
{
    const int i = blockIdx.x * 256 + threadIdx.x;      // over 1,572,864 float4s
    const float4 v = reinterpret_cast<const float4*>(x)[i];
    const float4 bd = reinterpret_cast<const float4*>(b_dec)[i % (DD / 4)];
    ushort4 h;
    h.x = f2bf(v.x - bd.x); h.y = f2bf(v.y - bd.y);
    h.z = f2bf(v.z - bd.z); h.w = f2bf(v.w - bd.w);
    reinterpret_cast<ushort4*>(xbf)[i] = h;
}

__global__ __launch_bounds__(256) void k0_cvt_bf(
    const float* __restrict__ src, unsigned short* __restrict__ dst)
{
    const int i = blockIdx.x * 256 + threadIdx.x;
    const float4 v = reinterpret_cast<const float4*>(src)[i];
    ushort4 h;
    h.x = f2bf(v.x); h.y = f2bf(v.y); h.z = f2bf(v.z); h.w = f2bf(v.w);
    reinterpret_cast<ushort4*>(dst)[i] = h;
}

// ---------------------------------------------------------------- K1a: gate
__global__ __launch_bounds__(256) void k1_gate(
    const float* __restrict__ x, const float* __restrict__ gate_W,
    const float* __restrict__ gate_b, const float* __restrict__ b_gate,
    int* __restrict__ eids, double* __restrict__ entw,
    int* __restrict__ rnk, int* __restrict__ blk_cnt,
    int* __restrict__ rnk0, int* __restrict__ blk_cnt0)
{
    __shared__ int cnt[NE];
    __shared__ int cnt0[NE];
    const int wid  = threadIdx.x >> 6;
    const int lane = threadIdx.x & 63;
    const int blk  = blockIdx.x;
    const int tok  = blk * 4 + wid;

    if (threadIdx.x < NE) { cnt[threadIdx.x] = 0; cnt0[threadIdx.x] = 0; }
    __syncthreads();

    double xv[12];
#pragma unroll
    for (int j = 0; j < 12; ++j) {
        const int k = j * 64 + lane;
        xv[j] = (double)x[(size_t)tok * DD + k] - (double)b_gate[k];
    }

    double myLogit = -1.0e300;
    for (int e = 0; e < NE; ++e) {
        double d = 0.0;
#pragma unroll
        for (int j = 0; j < 12; ++j)
            d += xv[j] * (double)gate_W[e * DD + j * 64 + lane];
#pragma unroll
        for (int off = 32; off > 0; off >>= 1)
            d += __shfl_xor(d, off);
        if (lane == e) myLogit = d + (double)gate_b[e];
    }

    double m = myLogit;
#pragma unroll
    for (int off = 8; off > 0; off >>= 1) {
        double o = __shfl_xor(m, off); m = (o > m) ? o : m;
    }
    double p = exp(myLogit - m);
    double ssum = p;
#pragma unroll
    for (int off = 8; off > 0; off >>= 1) ssum += __shfl_xor(ssum, off);
    const double score = p / ssum;

    const bool lt16 = (lane < NE);
    double m1 = score;
#pragma unroll
    for (int off = 8; off > 0; off >>= 1) {
        double o = __shfl_xor(m1, off); m1 = (o > m1) ? o : m1;
    }
    unsigned long long b0 = __ballot(lt16 && (score == m1));
    const int i0 = __ffsll(b0) - 1;
    double sc2 = (lane == i0) ? -1.0 : score;
    double m2 = sc2;
#pragma unroll
    for (int off = 8; off > 0; off >>= 1) {
        double o = __shfl_xor(m2, off); m2 = (o > m2) ? o : m2;
    }
    unsigned long long b1 = __ballot(lt16 && (sc2 == m2));
    const int i1 = __ffsll(b1) - 1;

    if (lane == 0) {
        const double w0 = 1.0 / (1.0 + exp(m2 - m1));
        const double w1 = 1.0 - w0;
        eids[tok * 2 + 0] = i0;
        eids[tok * 2 + 1] = i1;
        entw[tok * 2 + 0] = w0;
        entw[tok * 2 + 1] = w1;
        rnk[tok * 2 + 0] = atomicAdd(&cnt[i0], 1);
        rnk[tok * 2 + 1] = atomicAdd(&cnt[i1], 1);
        rnk0[tok] = atomicAdd(&cnt0[i0], 1);
    }
    __syncthreads();
    if (threadIdx.x < NE) {
        blk_cnt [threadIdx.x * K1BLK + blk] = cnt [threadIdx.x];
        blk_cnt0[threadIdx.x * K1BLK + blk] = cnt0[threadIdx.x];
    }
}

// ------------------------------------------- K1b: scan (32 blocks: 16 entry-lists, 16 slot0-order)
__global__ __launch_bounds__(256) void k1_scan(
    const int* __restrict__ bc,  int* __restrict__ bo,  int* __restrict__ counts,
    const int* __restrict__ bc0, int* __restrict__ bo0, int* __restrict__ counts0)
{
    __shared__ int tsum[256];
    const int g = blockIdx.x;
    const int e = g & 15;
    const int* src = (g >= NE) ? bc0 : bc;
    int* dst       = (g >= NE) ? bo0 : bo;
    int* cn        = (g >= NE) ? counts0 : counts;
    const int t = threadIdx.x;
    int loc[8]; int s = 0;
#pragma unroll
    for (int i = 0; i < 8; ++i) { loc[i] = s; s += src[e * K1BLK + t * 8 + i]; }
    tsum[t] = s;
    __syncthreads();
    for (int off = 1; off < 256; off <<= 1) {
        const int u = (t >= off) ? tsum[t - off] : 0;
        __syncthreads();
        tsum[t] += u;
        __syncthreads();
    }
    const int excl = tsum[t] - s;
#pragma unroll
    for (int i = 0; i < 8; ++i) dst[e * K1BLK + t * 8 + i] = excl + loc[i];
    if (t == 255) cn[e] = tsum[255];
}

// ---------------------------------------------------------------- K1c: scatter
__global__ __launch_bounds__(256) void k1_scatter(
    const int* __restrict__ eids, const int* __restrict__ rnk,
    const int* __restrict__ blk_off, int* __restrict__ lists,
    const int* __restrict__ rnk0, const int* __restrict__ blk_off0,
    const int* __restrict__ counts0, int* __restrict__ tokord)
{
    const int i = blockIdx.x * 256 + threadIdx.x;   // 16384 entries
    const int e = eids[i];
    const int blk = i >> 3;
    lists[e * MAXT + blk_off[e * K1BLK + blk] + rnk[i]] = i;
    if (!(i & 1)) {
        const int tok = i >> 1;
        int base0 = 0;
#pragma unroll
        for (int e2 = 0; e2 < NE; ++e2) base0 += (e2 < e) ? counts0[e2] : 0;
        tokord[base0 + blk_off0[e * K1BLK + blk] + rnk0[tok]] = tok;
    }
}

// ------------------------------------------------- K2: grouped expert GEMM
// pure-bf16, double-buffered LDS, all-async staging, counted vmcnt (T3+T4).
template<bool WBF>
__global__ __launch_bounds__(256, 2) void k2_encode(
    const unsigned short* __restrict__ xbf,
    const unsigned short* __restrict__ wbf,
    const float* __restrict__ expert_W,
    const float* __restrict__ expert_b,
    const int* __restrict__ counts, const int* __restrict__ lists,
    const double* __restrict__ entw, unsigned short* __restrict__ fbuf)
{
    const int e = blockIdx.z;
    const int cnt = counts[e];
    const int mbase = blockIdx.y * 128;
    if (mbase >= cnt) return;
    const int rows = min(128, cnt - mbase);
    const int nbase = blockIdx.x * 128;

    __shared__ char smem[65536];   // 2 buffers x (A 16KB | B 16KB)

    const int t = threadIdx.x;
    const int lane = t & 63;
    const int wid = t >> 6;
    const int wm = wid >> 1, wn = wid & 1;
    const int l15 = lane & 15, q = lane >> 4;
    const int rl = lane >> 3;          // row-within-8 for async staging
    const int cg = lane & 7;           // 16B chunk index
    const int xorc = (cg ^ rl) << 4;   // inverse-swizzled source chunk byte

    size_t asrc[4];
#pragma unroll
    for (int j = 0; j < 4; ++j) {
        const int r = (wid * 4 + j) * 8 + rl;
        const int rr = (r < rows) ? r : 0;
        const int tok = lists[e * MAXT + mbase + rr] >> 1;
        asrc[j] = (size_t)tok * (DD * 2) + xorc;
    }
    size_t bsrc[4];
#pragma unroll
    for (int j = 0; j < 4; ++j) {
        const int r = (wid * 4 + j) * 8 + rl;
        bsrc[j] = ((size_t)(e * EDD + nbase + r)) * (DD * 2) + xorc;
    }
    const int kq = t & 15, rg = t >> 4;   // !WBF B-convert map

    f32x4 acc[4][4];
#pragma unroll
    for (int a = 0; a < 4; ++a)
#pragma unroll
        for (int b = 0; b < 4; ++b)
            acc[a][b] = f32x4{0.f, 0.f, 0.f, 0.f};

    auto stageA = [&](int s, char* buf) {
#pragma unroll
        for (int j = 0; j < 4; ++j)
            async16((const char*)xbf + asrc[j] + (size_t)s * BKBYTES,
                    buf + ((wid * 4 + j) << 10));
    };
    auto stageB_async = [&](int s, char* buf) {
#pragma unroll
        for (int j = 0; j < 4; ++j)
            async16((const char*)wbf + bsrc[j] + (size_t)s * BKBYTES,
                    buf + 16384 + ((wid * 4 + j) << 10));
    };
    auto stageB_cvt = [&](int s, char* buf) {
#pragma unroll
        for (int j = 0; j < 8; ++j) {
            const int r = rg * 8 + j;
            const float4 bv = *reinterpret_cast<const float4*>(
                expert_W + ((size_t)e * EDD + nbase + r) * DD + s * 64 + kq * 4);
            ushort4 b4;
            b4.x = f2bf(bv.x); b4.y = f2bf(bv.y); b4.z = f2bf(bv.z); b4.w = f2bf(bv.w);
            *reinterpret_cast<ushort4*>(
                buf + 16384 + ((r * 128 + kq * 8) ^ ((r & 7) << 4))) = b4;
        }
    };
    auto compute = [&](char* buf) {
#pragma unroll
        for (int ks = 0; ks < 2; ++ks) {
            bf16x8 ah[4], bh[4];
#pragma unroll
            for (int fm = 0; fm < 4; ++fm) {
                const int row = wm * 64 + fm * 16 + l15;
                ah[fm] = *reinterpret_cast<const bf16x8*>(
                    buf + row * 128 + ((ks * 64 + q * 16) ^ ((row & 7) << 4)));
            }
#pragma unroll
            for (int fn = 0; fn < 4; ++fn) {
                const int row = wn * 64 + fn * 16 + l15;
                bh[fn] = *reinterpret_cast<const bf16x8*>(
                    buf + 16384 + row * 128 + ((ks * 64 + q * 16) ^ ((row & 7) << 4)));
            }
#pragma unroll
            for (int fm = 0; fm < 4; ++fm)
#pragma unroll
                for (int fn = 0; fn < 4; ++fn)
                    acc[fm][fn] = __builtin_amdgcn_mfma_f32_16x16x32_bf16(
                        ah[fm], bh[fn], acc[fm][fn], 0, 0, 0);
        }
    };

    // prologue: stage tile 0 into buffer 0
    if constexpr (WBF) {
        stageA(0, smem);
        stageB_async(0, smem);
    } else {
        stageB_cvt(0, smem);
        stageA(0, smem);
    }

    for (int s = 0; s < NSTEP; ++s) {
        char* cur = smem + ((s & 1) << 15);
        char* nxt = smem + (((s & 1) ^ 1) << 15);
        if (s + 1 < NSTEP) {
            if constexpr (WBF) {
                stageA(s + 1, nxt);
                stageB_async(s + 1, nxt);
                VMCNT8();              // retire tile s, keep tile s+1 in flight
            } else {
                stageB_cvt(s + 1, nxt);
                stageA(s + 1, nxt);
                VMCNT4();
            }
        } else {
            VMCNT0();
        }
        __syncthreads();
        compute(cur);
        __syncthreads();
    }

    // epilogue: C/D layout col=lane&15, row=(lane>>4)*4+reg; bias+relu+renorm; f16 out
#pragma unroll
    for (int fm = 0; fm < 4; ++fm) {
#pragma unroll
        for (int r = 0; r < 4; ++r) {
            const int ml = wm * 64 + fm * 16 + q * 4 + r;
            if (ml >= rows) continue;
            const int ent = lists[e * MAXT + mbase + ml];
            const float ren = (float)entw[ent];
            unsigned short* fout = fbuf + (size_t)ent * EDD + nbase;
#pragma unroll
            for (int fn = 0; fn < 4; ++fn) {
                const int nl = wn * 64 + fn * 16 + l15;
                float v = acc[fm][fn][r] + expert_b[e * EDD + nbase + nl];
                v = fmaxf(v, 0.f) * ren;
                fout[nl] = f2h_bits(v);
            }
        }
    }
}

// --------------------------- K3: per-token exact top-100 + fused decode
// expert-major token order + XCD-chunked dispatch; round-5 decode shape
// (24B/lane/row) with explicit 4-deep load/FMA software pipeline.
template<int DEC16>
__global__ __launch_bounds__(256) void k3_topk_decode(
    const float* __restrict__ x, const float* __restrict__ b_dec,
    const float* __restrict__ expert_W, const float* __restrict__ expert_b,
    const int* __restrict__ eids, const double* __restrict__ entw,
    const unsigned short* __restrict__ fbuf,
    const float* __restrict__ decoder, const unsigned short* __restrict__ dec16,
    const int* __restrict__ tokord, float* __restrict__ out)
{
    // XCD-chunked: each of 8 XCDs walks a contiguous 1024-token slice of the
    // expert-major order, so its L2 holds ~2 expert dict slices.
    const int bid = blockIdx.x;
    const int tok = tokord[(bid & 7) * (NB / 8) + (bid >> 3)];
    const int t = threadIdx.x;

    // arena overlay: [fv 6144 | hist 1024 | cidx 1024 | cval 2048] before decode;
    // red[4*768 floats = 12288] after selection (fv/hist/cidx/cval all dead then).
    __shared__ __align__(16) char arena[12288];
    unsigned short* fv   = (unsigned short*)arena;
    unsigned int*   hist = (unsigned int*)(arena + 6144);
    int*            cidx = (int*)(arena + 7168);
    double*         cval = (double*)(arena + 8192);
    float*          red  = (float*)arena;
    __shared__ int hb_s, T_s, rem_s, tz_s, nsel_s, ncand_s, total_s, need_s;
    __shared__ int   sel_didx[KTOP];
    __shared__ float sel_act[KTOP];

    const unsigned int* frow = reinterpret_cast<const unsigned int*>(fbuf + (size_t)tok * 2 * EDD);
#pragma unroll
    for (int i = 0; i < 6; ++i)
        reinterpret_cast<unsigned int*>(fv)[t + 256 * i] = frow[t + 256 * i];
    if (t == 0) { tz_s = 0; nsel_s = 0; ncand_s = 0; }
    hist[t] = 0u;
    __syncthreads();

    // pass 1: top byte of f16 bits (all values >= 0)
#pragma unroll
    for (int i = 0; i < 12; ++i) {
        const unsigned int u = fv[t + 256 * i];
        if (u) atomicAdd(&hist[u >> 8], 1u);
    }
    __syncthreads();
    if (t == 0) {
        unsigned int cum = 0; int v = 255;
        for (; v >= 0; --v) { const unsigned int c = hist[v]; if (cum + c >= KTOP) break; cum += c; }
        if (v < 0) tz_s = 1;
        else { hb_s = v; rem_s = KTOP - (int)cum; }
    }
    __syncthreads();

    if (!tz_s) {
        hist[t] = 0u;
        __syncthreads();
        const unsigned int hb = (unsigned int)hb_s;
#pragma unroll
        for (int i = 0; i < 12; ++i) {
            const unsigned int u = fv[t + 256 * i];
            if (u && (u >> 8) == hb) atomicAdd(&hist[u & 255u], 1u);
        }
        __syncthreads();
        if (t == 0) {
            const int rem = rem_s; unsigned int cum = 0; int v = 255;
            for (; v >= 0; --v) { const unsigned int c = hist[v]; if (cum + c >= (unsigned int)rem) break; cum += c; }
            T_s = (hb_s << 8) | v;
        }
        __syncthreads();
    }

    if (tz_s) {
        // fewer than 100 positives: take them all (rest are exact zeros)
#pragma unroll
        for (int i = 0; i < 12; ++i) {
            const int j = t + 256 * i;
            const unsigned int u = fv[j];
            if (u) {
                const int p = atomicAdd(&nsel_s, 1);
                const int slot = (j >= EDD) ? 1 : 0;
                const int n = j - slot * EDD;
                sel_didx[p] = eids[tok * 2 + slot] * EDD + n;
                sel_act[p] = h2f_bits((unsigned short)u);
            }
        }
        __syncthreads();
        if (t == 0) total_s = nsel_s;
        __syncthreads();
    } else {
        const int T = T_s;
#pragma unroll
        for (int i = 0; i < 12; ++i) {
            const int j = t + 256 * i;
            const unsigned int u = fv[j];
            if ((int)u >= T + CONF_ULP) {
                const int p = atomicAdd(&nsel_s, 1);
                const int slot = (j >= EDD) ? 1 : 0;
                const int n = j - slot * EDD;
                sel_didx[p] = eids[tok * 2 + slot] * EDD + n;
                sel_act[p] = h2f_bits((unsigned short)u);
            } else if (u != 0u && (int)u + BAND_ULP >= T) {
                const int c = atomicAdd(&ncand_s, 1);
                if (c < CAND_MAX) cidx[c] = j;
            }
        }
        __syncthreads();

        // fp64 re-evaluation of candidates, one wave per candidate
        {
            const int ncand = min(ncand_s, CAND_MAX);
            const int wv = t >> 6, lane = t & 63;
            for (int c = wv; c < ncand; c += 4) {
                const int j = cidx[c];
                const int slot = (j >= EDD) ? 1 : 0;
                const int n = j - slot * EDD;
                const int ee = eids[tok * 2 + slot];
                const float* wr = expert_W + ((size_t)ee * EDD + n) * DD;
                const float* xr = x + (size_t)tok * DD;
                double d = 0.0;
#pragma unroll
                for (int jj = 0; jj < 12; ++jj) {
                    const int k = jj * 64 + lane;
                    d += ((double)xr[k] - (double)b_dec[k]) * (double)wr[k];
                }
#pragma unroll
                for (int off = 32; off > 0; off >>= 1) d += __shfl_xor(d, off);
                if (lane == 0) {
                    double z = d + (double)expert_b[ee * EDD + n];
                    if (z < 0.0) z = 0.0;
                    cval[c] = z * entw[tok * 2 + slot];
                }
            }
        }
        __syncthreads();
        if (t == 0) {
            const int ncand = min(ncand_s, CAND_MAX);
            int need = KTOP - nsel_s;
            if (need > ncand) need = ncand;
            if (need < 0) need = 0;
            need_s = need;
            total_s = nsel_s + need;
        }
        __syncthreads();

        // parallel rank-based selection among candidates (value desc, dict idx asc)
        {
            const int ncand = min(ncand_s, CAND_MAX);
            if (t < ncand) {
                const int j = cidx[t];
                const int slot = (j >= EDD) ? 1 : 0;
                const int my_didx = eids[tok * 2 + slot] * EDD + (j - slot * EDD);
                const double v = cval[t];
                int rank = 0;
                for (int i = 0; i < ncand; ++i) {
                    const int ji = cidx[i];
                    const int si = (ji >= EDD) ? 1 : 0;
                    const int di = eids[tok * 2 + si] * EDD + (ji - si * EDD);
                    const double vi = cval[i];
                    rank += (vi > v) || (vi == v && di < my_didx);
                }
                if (rank < need_s) {
                    sel_didx[nsel_s + rank] = my_didx;
                    sel_act[nsel_s + rank] = (float)v;
                }
            }
        }
        __syncthreads();
    }

    // fused decode: 4-wave k-split, 24B/lane/row, explicit 4-deep
    // load-then-FMA pipeline (12 independent gathers in flight per wave).
    const int total = total_s;
    const int wv = t >> 6;
    const int lane = t & 63;
    float accd[12];
#pragma unroll
    for (int i = 0; i < 12; ++i) accd[i] = 0.f;

    if (DEC16) {
        auto ldrow = [&](int k, float& a, ushort4& u0, ushort4& u1, ushort4& u2) {
            a = sel_act[k];
            const char* dr = (const char*)(dec16 + (size_t)sel_didx[k] * DD) + lane * 24;
            u0 = *reinterpret_cast<const ushort4*>(dr);
            u1 = *reinterpret_cast<const ushort4*>(dr + 8);
            u2 = *reinterpret_cast<const ushort4*>(dr + 16);
        };
        auto fmarow = [&](float a, ushort4 u0, ushort4 u1, ushort4 u2) {
            accd[0] += a * bf2f(u0.x);  accd[1]  += a * bf2f(u0.y);
            accd[2] += a * bf2f(u0.z);  accd[3]  += a * bf2f(u0.w);
            accd[4] += a * bf2f(u1.x);  accd[5]  += a * bf2f(u1.y);
            accd[6] += a * bf2f(u1.z);  accd[7]  += a * bf2f(u1.w);
            accd[8] += a * bf2f(u2.x);  accd[9]  += a * bf2f(u2.y);
            accd[10] += a * bf2f(u2.z); accd[11] += a * bf2f(u2.w);
        };
        int k = wv;
        for (; k + 12 < total; k += 16) {
            float a0, a1, a2, a3;
            ushort4 p00, p01, p02, p10, p11, p12, p20, p21, p22, p30, p31, p32;
            ldrow(k,      a0, p00, p01, p02);
            ldrow(k + 4,  a1, p10, p11, p12);
            ldrow(k + 8,  a2, p20, p21, p22);
            ldrow(k + 12, a3, p30, p31, p32);
            fmarow(a0, p00, p01, p02);
            fmarow(a1, p10, p11, p12);
            fmarow(a2, p20, p21, p22);
            fmarow(a3, p30, p31, p32);
        }
        for (; k < total; k += 4) {
            float a; ushort4 q0, q1, q2;
            ldrow(k, a, q0, q1, q2);
            fmarow(a, q0, q1, q2);
        }
    } else {
        auto body = [&](int k) {
            const float a = sel_act[k];
            const float* dr = decoder + (size_t)sel_didx[k] * DD + lane * 12;
            const float4 f0 = *reinterpret_cast<const float4*>(dr);
            const float4 f1 = *reinterpret_cast<const float4*>(dr + 4);
            const float4 f2 = *reinterpret_cast<const float4*>(dr + 8);
            accd[0] += a * f0.x;  accd[1]  += a * f0.y;
            accd[2] += a * f0.z;  accd[3]  += a * f0.w;
            accd[4] += a * f1.x;  accd[5]  += a * f1.y;
            accd[6] += a * f1.z;  accd[7]  += a * f1.w;
            accd[8] += a * f2.x;  accd[9]  += a * f2.y;
            accd[10] += a * f2.z; accd[11] += a * f2.w;
        };
        int k = wv;
        for (; k + 4 < total; k += 8) { body(k); body(k + 4); }
        if (k < total) body(k);
    }

    // red overlays the arena — all reads of fv/cval are complete by here
#pragma unroll
    for (int i = 0; i < 12; ++i)
        red[wv * DD + lane * 12 + i] = accd[i];
    __syncthreads();
#pragma unroll
    for (int i = 0; i < 3; ++i) {
        const int j = t + 256 * i;
        out[(size_t)tok * DD + j] =
            red[j] + red[DD + j] + red[2 * DD + j] + red[3 * DD + j] + b_dec[j];
    }
}

// sentinel fill if workspace is too small (diagnosable: absmax ~ 12345)
__global__ void k_sentinel(float* __restrict__ out, int n) {
    int i = blockIdx.x * blockDim.x + threadIdx.x;
    if (i < n) out[i] = 12345.0f;
}

extern "C" void kernel_launch(void* const* d_in, const int* in_sizes, int n_in,
                              void* d_out, int out_size, void* d_ws, size_t ws_size,
                              hipStream_t stream)
{
    (void)in_sizes; (void)n_in;
    const float* x        = (const float*)d_in[0];
    const float* gate_W   = (const float*)d_in[1];
    const float* gate_b   = (const float*)d_in[2];
    const float* b_gate   = (const float*)d_in[3];
    const float* b_dec    = (const float*)d_in[4];
    const float* expert_W = (const float*)d_in[5];
    const float* expert_b = (const float*)d_in[6];
    const float* decoder  = (const float*)d_in[7];
    float* out = (float*)d_out;

    char* ws = (char*)d_ws;
    const size_t off_counts0 = 64;
    const size_t off_blkcnt = 256;
    const size_t off_blkoff = off_blkcnt + (size_t)NE * K1BLK * 4;
    const size_t off_rnk    = off_blkoff + (size_t)NE * K1BLK * 4;
    const size_t off_eids   = off_rnk    + (size_t)NB * 2 * 4;
    const size_t off_entw   = off_eids   + (size_t)NB * 2 * 4;
    const size_t off_lists  = off_entw   + (size_t)NB * 2 * 8;
    const size_t off_fbuf   = off_lists  + (size_t)NE * MAXT * 4;
    const size_t off_xbf    = off_fbuf   + (size_t)NB * 2 * EDD * 2;
    const size_t off_bc0    = off_xbf    + (size_t)NB * DD * 2;
    const size_t off_bo0    = off_bc0    + (size_t)NE * K1BLK * 4;
    const size_t off_rnk0   = off_bo0    + (size_t)NE * K1BLK * 4;
    const size_t off_tokord = off_rnk0   + (size_t)NB * 4;
    const size_t base_end   = off_tokord + (size_t)NB * 4;           // ~64.4 MB
    const size_t WSZ        = (size_t)NE * EDD * DD * 2;             // 37.75 MB

    if (ws_size < base_end) {
        k_sentinel<<<(out_size + 255) / 256, 256, 0, stream>>>(out, out_size);
        return;
    }
    size_t off = base_end;
    const bool have_w = (ws_size >= off + WSZ);
    unsigned short* wbf = have_w ? (unsigned short*)(ws + off) : nullptr;
    if (have_w) off += WSZ;
    const bool have_d = (ws_size >= off + WSZ);
    unsigned short* dec16v = have_d ? (unsigned short*)(ws + off) : nullptr;

    int*            counts  = (int*)ws;
    int*            counts0 = (int*)(ws + off_counts0);
    int*            blk_cnt = (int*)(ws + off_blkcnt);
    int*            blk_off = (int*)(ws + off_blkoff);
    int*            rnk     = (int*)(ws + off_rnk);
    int*            eids    = (int*)(ws + off_eids);
    double*         entw    = (double*)(ws + off_entw);
    int*            lists   = (int*)(ws + off_lists);
    unsigned short* fbuf    = (unsigned short*)(ws + off_fbuf);
    unsigned short* xbf     = (unsigned short*)(ws + off_xbf);
    int*            blk_cnt0= (int*)(ws + off_bc0);
    int*            blk_off0= (int*)(ws + off_bo0);
    int*            rnk0    = (int*)(ws + off_rnk0);
    int*            tokord  = (int*)(ws + off_tokord);

    hipMemsetAsync(counts, 0, 128, stream);

    k0_prep_x<<<(NB * DD / 4) / 256, 256, 0, stream>>>(x, b_dec, xbf);
    const int n4blocks = (NE * EDD * DD / 4) / 256;   // 18432
    if (have_w)
        k0_cvt_bf<<<n4blocks, 256, 0, stream>>>(expert_W, wbf);
    if (have_d)
        k0_cvt_bf<<<n4blocks, 256, 0, stream>>>(decoder, dec16v);

    k1_gate<<<K1BLK, 256, 0, stream>>>(x, gate_W, gate_b, b_gate, eids, entw,
                                       rnk, blk_cnt, rnk0, blk_cnt0);
    k1_scan<<<2 * NE, 256, 0, stream>>>(blk_cnt, blk_off, counts,
                                        blk_cnt0, blk_off0, counts0);
    k1_scatter<<<NB * 2 / 256, 256, 0, stream>>>(eids, rnk, blk_off, lists,
                                                 rnk0, blk_off0, counts0, tokord);

    dim3 g2(EDD / 128, MAXT / 128, NE);   // (ntile=12, mtile=64, e=16), early-exit
    if (have_w)
        k2_encode<true><<<g2, 256, 0, stream>>>(xbf, wbf, expert_W, expert_b,
                                                counts, lists, entw, fbuf);
    else
        k2_encode<false><<<g2, 256, 0, stream>>>(xbf, wbf, expert_W, expert_b,
                                                 counts, lists, entw, fbuf);

    if (have_d)
        k3_topk_decode<1><<<NB, 256, 0, stream>>>(x, b_dec, expert_W, expert_b, eids,
                                                  entw, fbuf, decoder, dec16v, tokord, out);
    else
        k3_topk_decode<0><<<NB, 256, 0, stream>>>(x, b_dec, expert_W, expert_b, eids,
                                                  entw, fbuf, decoder, dec16v, tokord, out);
}

// Round 8
// 386.312 us; speedup vs baseline: 1.1430x; 1.0613x over previous
//
#include <hip/hip_runtime.h>
#include <hip/hip_fp16.h>
#include <cstdint>
#include <cstddef>

#define NB    8192
#define DD    768
#define NE    16
#define EDD   1536
#define KTOP  100
#define MAXT  8192
#define CAND_MAX 256
#define K1BLK 2048
#define NSTEP 12
#define BKBYTES 128      // 64 k * 2B
#define CONF_ULP 21
#define BAND_ULP 20

typedef __attribute__((ext_vector_type(4))) float f32x4;
typedef __attribute__((ext_vector_type(8))) short bf16x8;

#define VMCNT8() asm volatile("s_waitcnt vmcnt(8)" ::: "memory")
#define VMCNT4() asm volatile("s_waitcnt vmcnt(4)" ::: "memory")
#define VMCNT0() asm volatile("s_waitcnt vmcnt(0)" ::: "memory")

__device__ __forceinline__ unsigned short f2bf(float v) {
    unsigned int u = __float_as_uint(v);
    u += 0x7FFFu + ((u >> 16) & 1u);   // RNE to bf16
    return (unsigned short)(u >> 16);
}
__device__ __forceinline__ float bf2f(unsigned short h) {
    return __uint_as_float(((unsigned int)h) << 16);
}
__device__ __forceinline__ unsigned short f2h_bits(float v) {
    return __half_as_ushort(__float2half(v));
}
__device__ __forceinline__ float h2f_bits(unsigned short b) {
    return __half2float(__ushort_as_half(b));
}
__device__ __forceinline__ void async16(const void* g, void* l) {
    __builtin_amdgcn_global_load_lds(
        (const __attribute__((address_space(1))) unsigned int*)g,
        (__attribute__((address_space(3))) unsigned int*)l, 16, 0, 0);
}

// ---------------------------------------------------------------- K0: converts
__global__ __launch_bounds__(256) void k0_prep_x(
    const float* __restrict__ x, const float* __restrict__ b_dec,
    unsigned short* __restrict__ xbf)
{
    const int i = blockIdx.x * 256 + threadIdx.x;      // over 1,572,864 float4s
    const float4 v = reinterpret_cast<const float4*>(x)[i];
    const float4 bd = reinterpret_cast<const float4*>(b_dec)[i % (DD / 4)];
    ushort4 h;
    h.x = f2bf(v.x - bd.x); h.y = f2bf(v.y - bd.y);
    h.z = f2bf(v.z - bd.z); h.w = f2bf(v.w - bd.w);
    reinterpret_cast<ushort4*>(xbf)[i] = h;
}

__global__ __launch_bounds__(256) void k0_cvt_bf(
    const float* __restrict__ src, unsigned short* __restrict__ dst)
{
    const int i = blockIdx.x * 256 + threadIdx.x;
    const float4 v = reinterpret_cast<const float4*>(src)[i];
    ushort4 h;
    h.x = f2bf(v.x); h.y = f2bf(v.y); h.z = f2bf(v.z); h.w = f2bf(v.w);
    reinterpret_cast<ushort4*>(dst)[i] = h;
}

// ---------------------------------------------------------------- K1a: gate
__global__ __launch_bounds__(256) void k1_gate(
    const float* __restrict__ x, const float* __restrict__ gate_W,
    const float* __restrict__ gate_b, const float* __restrict__ b_gate,
    int* __restrict__ eids, double* __restrict__ entw,
    int* __restrict__ rnk, int* __restrict__ blk_cnt,
    int* __restrict__ rnk0, int* __restrict__ blk_cnt0)
{
    __shared__ int cnt[NE];
    __shared__ int cnt0[NE];
    const int wid  = threadIdx.x >> 6;
    const int lane = threadIdx.x & 63;
    const int blk  = blockIdx.x;
    const int tok  = blk * 4 + wid;

    if (threadIdx.x < NE) { cnt[threadIdx.x] = 0; cnt0[threadIdx.x] = 0; }
    __syncthreads();

    double xv[12];
#pragma unroll
    for (int j = 0; j < 12; ++j) {
        const int k = j * 64 + lane;
        xv[j] = (double)x[(size_t)tok * DD + k] - (double)b_gate[k];
    }

    double myLogit = -1.0e300;
    for (int e = 0; e < NE; ++e) {
        double d = 0.0;
#pragma unroll
        for (int j = 0; j < 12; ++j)
            d += xv[j] * (double)gate_W[e * DD + j * 64 + lane];
#pragma unroll
        for (int off = 32; off > 0; off >>= 1)
            d += __shfl_xor(d, off);
        if (lane == e) myLogit = d + (double)gate_b[e];
    }

    double m = myLogit;
#pragma unroll
    for (int off = 8; off > 0; off >>= 1) {
        double o = __shfl_xor(m, off); m = (o > m) ? o : m;
    }
    double p = exp(myLogit - m);
    double ssum = p;
#pragma unroll
    for (int off = 8; off > 0; off >>= 1) ssum += __shfl_xor(ssum, off);
    const double score = p / ssum;

    const bool lt16 = (lane < NE);
    double m1 = score;
#pragma unroll
    for (int off = 8; off > 0; off >>= 1) {
        double o = __shfl_xor(m1, off); m1 = (o > m1) ? o : m1;
    }
    unsigned long long b0 = __ballot(lt16 && (score == m1));
    const int i0 = __ffsll(b0) - 1;
    double sc2 = (lane == i0) ? -1.0 : score;
    double m2 = sc2;
#pragma unroll
    for (int off = 8; off > 0; off >>= 1) {
        double o = __shfl_xor(m2, off); m2 = (o > m2) ? o : m2;
    }
    unsigned long long b1 = __ballot(lt16 && (sc2 == m2));
    const int i1 = __ffsll(b1) - 1;

    if (lane == 0) {
        const double w0 = 1.0 / (1.0 + exp(m2 - m1));
        const double w1 = 1.0 - w0;
        eids[tok * 2 + 0] = i0;
        eids[tok * 2 + 1] = i1;
        entw[tok * 2 + 0] = w0;
        entw[tok * 2 + 1] = w1;
        rnk[tok * 2 + 0] = atomicAdd(&cnt[i0], 1);
        rnk[tok * 2 + 1] = atomicAdd(&cnt[i1], 1);
        rnk0[tok] = atomicAdd(&cnt0[i0], 1);
    }
    __syncthreads();
    if (threadIdx.x < NE) {
        blk_cnt [threadIdx.x * K1BLK + blk] = cnt [threadIdx.x];
        blk_cnt0[threadIdx.x * K1BLK + blk] = cnt0[threadIdx.x];
    }
}

// ------------------------------------------- K1b: scan (32 blocks: 16 entry-lists, 16 slot0-order)
__global__ __launch_bounds__(256) void k1_scan(
    const int* __restrict__ bc,  int* __restrict__ bo,  int* __restrict__ counts,
    const int* __restrict__ bc0, int* __restrict__ bo0, int* __restrict__ counts0)
{
    __shared__ int tsum[256];
    const int g = blockIdx.x;
    const int e = g & 15;
    const int* src = (g >= NE) ? bc0 : bc;
    int* dst       = (g >= NE) ? bo0 : bo;
    int* cn        = (g >= NE) ? counts0 : counts;
    const int t = threadIdx.x;
    int loc[8]; int s = 0;
#pragma unroll
    for (int i = 0; i < 8; ++i) { loc[i] = s; s += src[e * K1BLK + t * 8 + i]; }
    tsum[t] = s;
    __syncthreads();
    for (int off = 1; off < 256; off <<= 1) {
        const int u = (t >= off) ? tsum[t - off] : 0;
        __syncthreads();
        tsum[t] += u;
        __syncthreads();
    }
    const int excl = tsum[t] - s;
#pragma unroll
    for (int i = 0; i < 8; ++i) dst[e * K1BLK + t * 8 + i] = excl + loc[i];
    if (t == 255) cn[e] = tsum[255];
}

// ---------------------------------------------------------------- K1c: scatter
__global__ __launch_bounds__(256) void k1_scatter(
    const int* __restrict__ eids, const int* __restrict__ rnk,
    const int* __restrict__ blk_off, int* __restrict__ lists,
    const int* __restrict__ rnk0, const int* __restrict__ blk_off0,
    const int* __restrict__ counts0, int* __restrict__ tokord)
{
    const int i = blockIdx.x * 256 + threadIdx.x;   // 16384 entries
    const int e = eids[i];
    const int blk = i >> 3;
    lists[e * MAXT + blk_off[e * K1BLK + blk] + rnk[i]] = i;
    if (!(i & 1)) {
        const int tok = i >> 1;
        int base0 = 0;
#pragma unroll
        for (int e2 = 0; e2 < NE; ++e2) base0 += (e2 < e) ? counts0[e2] : 0;
        tokord[base0 + blk_off0[e * K1BLK + blk] + rnk0[tok]] = tok;
    }
}

// ------------------------------------------------- K2: grouped expert GEMM
// pure-bf16, double-buffered LDS, all-async staging, counted vmcnt (T3+T4).
template<bool WBF>
__global__ __launch_bounds__(256, 2) void k2_encode(
    const unsigned short* __restrict__ xbf,
    const unsigned short* __restrict__ wbf,
    const float* __restrict__ expert_W,
    const float* __restrict__ expert_b,
    const int* __restrict__ counts, const int* __restrict__ lists,
    const double* __restrict__ entw, unsigned short* __restrict__ fbuf)
{
    const int e = blockIdx.z;
    const int cnt = counts[e];
    const int mbase = blockIdx.y * 128;
    if (mbase >= cnt) return;
    const int rows = min(128, cnt - mbase);
    const int nbase = blockIdx.x * 128;

    __shared__ char smem[65536];   // 2 buffers x (A 16KB | B 16KB)

    const int t = threadIdx.x;
    const int lane = t & 63;
    const int wid = t >> 6;
    const int wm = wid >> 1, wn = wid & 1;
    const int l15 = lane & 15, q = lane >> 4;
    const int rl = lane >> 3;          // row-within-8 for async staging
    const int cg = lane & 7;           // 16B chunk index
    const int xorc = (cg ^ rl) << 4;   // inverse-swizzled source chunk byte

    size_t asrc[4];
#pragma unroll
    for (int j = 0; j < 4; ++j) {
        const int r = (wid * 4 + j) * 8 + rl;
        const int rr = (r < rows) ? r : 0;
        const int tok = lists[e * MAXT + mbase + rr] >> 1;
        asrc[j] = (size_t)tok * (DD * 2) + xorc;
    }
    size_t bsrc[4];
#pragma unroll
    for (int j = 0; j < 4; ++j) {
        const int r = (wid * 4 + j) * 8 + rl;
        bsrc[j] = ((size_t)(e * EDD + nbase + r)) * (DD * 2) + xorc;
    }
    const int kq = t & 15, rg = t >> 4;   // !WBF B-convert map

    f32x4 acc[4][4];
#pragma unroll
    for (int a = 0; a < 4; ++a)
#pragma unroll
        for (int b = 0; b < 4; ++b)
            acc[a][b] = f32x4{0.f, 0.f, 0.f, 0.f};

    auto stageA = [&](int s, char* buf) {
#pragma unroll
        for (int j = 0; j < 4; ++j)
            async16((const char*)xbf + asrc[j] + (size_t)s * BKBYTES,
                    buf + ((wid * 4 + j) << 10));
    };
    auto stageB_async = [&](int s, char* buf) {
#pragma unroll
        for (int j = 0; j < 4; ++j)
            async16((const char*)wbf + bsrc[j] + (size_t)s * BKBYTES,
                    buf + 16384 + ((wid * 4 + j) << 10));
    };
    auto stageB_cvt = [&](int s, char* buf) {
#pragma unroll
        for (int j = 0; j < 8; ++j) {
            const int r = rg * 8 + j;
            const float4 bv = *reinterpret_cast<const float4*>(
                expert_W + ((size_t)e * EDD + nbase + r) * DD + s * 64 + kq * 4);
            ushort4 b4;
            b4.x = f2bf(bv.x); b4.y = f2bf(bv.y); b4.z = f2bf(bv.z); b4.w = f2bf(bv.w);
            *reinterpret_cast<ushort4*>(
                buf + 16384 + ((r * 128 + kq * 8) ^ ((r & 7) << 4))) = b4;
        }
    };
    auto compute = [&](char* buf) {
#pragma unroll
        for (int ks = 0; ks < 2; ++ks) {
            bf16x8 ah[4], bh[4];
#pragma unroll
            for (int fm = 0; fm < 4; ++fm) {
                const int row = wm * 64 + fm * 16 + l15;
                ah[fm] = *reinterpret_cast<const bf16x8*>(
                    buf + row * 128 + ((ks * 64 + q * 16) ^ ((row & 7) << 4)));
            }
#pragma unroll
            for (int fn = 0; fn < 4; ++fn) {
                const int row = wn * 64 + fn * 16 + l15;
                bh[fn] = *reinterpret_cast<const bf16x8*>(
                    buf + 16384 + row * 128 + ((ks * 64 + q * 16) ^ ((row & 7) << 4)));
            }
#pragma unroll
            for (int fm = 0; fm < 4; ++fm)
#pragma unroll
                for (int fn = 0; fn < 4; ++fn)
                    acc[fm][fn] = __builtin_amdgcn_mfma_f32_16x16x32_bf16(
                        ah[fm], bh[fn], acc[fm][fn], 0, 0, 0);
        }
    };

    // prologue: stage tile 0 into buffer 0
    if constexpr (WBF) {
        stageA(0, smem);
        stageB_async(0, smem);
    } else {
        stageB_cvt(0, smem);
        stageA(0, smem);
    }

    for (int s = 0; s < NSTEP; ++s) {
        char* cur = smem + ((s & 1) << 15);
        char* nxt = smem + (((s & 1) ^ 1) << 15);
        if (s + 1 < NSTEP) {
            if constexpr (WBF) {
                stageA(s + 1, nxt);
                stageB_async(s + 1, nxt);
                VMCNT8();              // retire tile s, keep tile s+1 in flight
            } else {
                stageB_cvt(s + 1, nxt);
                stageA(s + 1, nxt);
                VMCNT4();
            }
        } else {
            VMCNT0();
        }
        __syncthreads();
        compute(cur);
        __syncthreads();
    }

    // epilogue: C/D layout col=lane&15, row=(lane>>4)*4+reg; bias+relu+renorm; f16 out
#pragma unroll
    for (int fm = 0; fm < 4; ++fm) {
#pragma unroll
        for (int r = 0; r < 4; ++r) {
            const int ml = wm * 64 + fm * 16 + q * 4 + r;
            if (ml >= rows) continue;
            const int ent = lists[e * MAXT + mbase + ml];
            const float ren = (float)entw[ent];
            unsigned short* fout = fbuf + (size_t)ent * EDD + nbase;
#pragma unroll
            for (int fn = 0; fn < 4; ++fn) {
                const int nl = wn * 64 + fn * 16 + l15;
                float v = acc[fm][fn][r] + expert_b[e * EDD + nbase + nl];
                v = fmaxf(v, 0.f) * ren;
                fout[nl] = f2h_bits(v);
            }
        }
    }
}

// --------------------------- K3: per-token exact top-100 + fused decode
// 512 threads (8 waves); parallel suffix-scan radix thresholds (no serial
// t==0 loops); expert-major token order + XCD-chunked dispatch.
template<int DEC16>
__global__ __launch_bounds__(512) void k3_topk_decode(
    const float* __restrict__ x, const float* __restrict__ b_dec,
    const float* __restrict__ expert_W, const float* __restrict__ expert_b,
    const int* __restrict__ eids, const double* __restrict__ entw,
    const unsigned short* __restrict__ fbuf,
    const float* __restrict__ decoder, const unsigned short* __restrict__ dec16,
    const int* __restrict__ tokord, float* __restrict__ out)
{
    const int bid = blockIdx.x;
    const int tok = tokord[(bid & 7) * (NB / 8) + (bid >> 3)];
    const int t = threadIdx.x;

    // arena overlay: [fv 6144 | hist 1024 | cidx 1024 | cval 2048] before decode;
    // red[8*768 floats = 24576] after selection (all earlier arrays dead then).
    __shared__ __align__(16) char arena[24576];
    unsigned short* fv   = (unsigned short*)arena;
    unsigned int*   hist = (unsigned int*)(arena + 6144);
    int*            cidx = (int*)(arena + 7168);
    double*         cval = (double*)(arena + 8192);
    float*          red  = (float*)arena;
    __shared__ unsigned int sc[256];
    __shared__ int hb_s, T_s, rem_s, tz_s, nsel_s, ncand_s, total_s, need_s;
    __shared__ int   sel_didx[KTOP];
    __shared__ float sel_act[KTOP];

    const unsigned int* frow = reinterpret_cast<const unsigned int*>(fbuf + (size_t)tok * 2 * EDD);
#pragma unroll
    for (int i = 0; i < 3; ++i)
        reinterpret_cast<unsigned int*>(fv)[t + 512 * i] = frow[t + 512 * i];
    if (t == 0) { tz_s = 0; nsel_s = 0; ncand_s = 0; }
    if (t < 256) hist[t] = 0u;
    __syncthreads();

    // pass 1: top byte of f16 bits (all values >= 0)
#pragma unroll
    for (int i = 0; i < 6; ++i) {
        const unsigned int u = fv[t + 512 * i];
        if (u) atomicAdd(&hist[u >> 8], 1u);
    }
    __syncthreads();
    // parallel suffix scan: sc[v] = sum_{u>=v} hist[u]
    if (t < 256) sc[t] = hist[t];
    __syncthreads();
    for (int off = 1; off < 256; off <<= 1) {
        const unsigned int v2 = (t < 256 - off) ? sc[t + off] : 0u;
        __syncthreads();
        if (t < 256) sc[t] += v2;
        __syncthreads();
    }
    if (t < 256) {
        const unsigned int above = (t == 255) ? 0u : sc[t + 1];
        if (sc[t] >= KTOP && above < KTOP) { hb_s = t; rem_s = KTOP - (int)above; }
    }
    if (t == 0 && sc[0] < KTOP) tz_s = 1;
    __syncthreads();

    if (!tz_s) {
        if (t < 256) hist[t] = 0u;
        __syncthreads();
        const unsigned int hb = (unsigned int)hb_s;
#pragma unroll
        for (int i = 0; i < 6; ++i) {
            const unsigned int u = fv[t + 512 * i];
            if (u && (u >> 8) == hb) atomicAdd(&hist[u & 255u], 1u);
        }
        __syncthreads();
        if (t < 256) sc[t] = hist[t];
        __syncthreads();
        for (int off = 1; off < 256; off <<= 1) {
            const unsigned int v2 = (t < 256 - off) ? sc[t + off] : 0u;
            __syncthreads();
            if (t < 256) sc[t] += v2;
            __syncthreads();
        }
        if (t < 256) {
            const unsigned int rem = (unsigned int)rem_s;
            const unsigned int above = (t == 255) ? 0u : sc[t + 1];
            if (sc[t] >= rem && above < rem) T_s = (hb_s << 8) | t;
        }
        __syncthreads();
    }

    if (tz_s) {
        // fewer than 100 positives: take them all (rest are exact zeros)
#pragma unroll
        for (int i = 0; i < 6; ++i) {
            const int j = t + 512 * i;
            const unsigned int u = fv[j];
            if (u) {
                const int p = atomicAdd(&nsel_s, 1);
                const int slot = (j >= EDD) ? 1 : 0;
                const int n = j - slot * EDD;
                sel_didx[p] = eids[tok * 2 + slot] * EDD + n;
                sel_act[p] = h2f_bits((unsigned short)u);
            }
        }
        __syncthreads();
        if (t == 0) total_s = nsel_s;
        __syncthreads();
    } else {
        const int T = T_s;
#pragma unroll
        for (int i = 0; i < 6; ++i) {
            const int j = t + 512 * i;
            const unsigned int u = fv[j];
            if ((int)u >= T + CONF_ULP) {
                const int p = atomicAdd(&nsel_s, 1);
                const int slot = (j >= EDD) ? 1 : 0;
                const int n = j - slot * EDD;
                sel_didx[p] = eids[tok * 2 + slot] * EDD + n;
                sel_act[p] = h2f_bits((unsigned short)u);
            } else if (u != 0u && (int)u + BAND_ULP >= T) {
                const int c = atomicAdd(&ncand_s, 1);
                if (c < CAND_MAX) cidx[c] = j;
            }
        }
        __syncthreads();

        // fp64 re-evaluation of candidates, one wave per candidate (8 waves)
        {
            const int ncand = min(ncand_s, CAND_MAX);
            const int wv = t >> 6, lane = t & 63;
            for (int c = wv; c < ncand; c += 8) {
                const int j = cidx[c];
                const int slot = (j >= EDD) ? 1 : 0;
                const int n = j - slot * EDD;
                const int ee = eids[tok * 2 + slot];
                const float* wr = expert_W + ((size_t)ee * EDD + n) * DD;
                const float* xr = x + (size_t)tok * DD;
                double d = 0.0;
#pragma unroll
                for (int jj = 0; jj < 12; ++jj) {
                    const int k = jj * 64 + lane;
                    d += ((double)xr[k] - (double)b_dec[k]) * (double)wr[k];
                }
#pragma unroll
                for (int off = 32; off > 0; off >>= 1) d += __shfl_xor(d, off);
                if (lane == 0) {
                    double z = d + (double)expert_b[ee * EDD + n];
                    if (z < 0.0) z = 0.0;
                    cval[c] = z * entw[tok * 2 + slot];
                }
            }
        }
        __syncthreads();
        if (t == 0) {
            const int ncand = min(ncand_s, CAND_MAX);
            int need = KTOP - nsel_s;
            if (need > ncand) need = ncand;
            if (need < 0) need = 0;
            need_s = need;
            total_s = nsel_s + need;
        }
        __syncthreads();

        // parallel rank-based selection among candidates (value desc, dict idx asc)
        {
            const int ncand = min(ncand_s, CAND_MAX);
            if (t < ncand) {
                const int j = cidx[t];
                const int slot = (j >= EDD) ? 1 : 0;
                const int my_didx = eids[tok * 2 + slot] * EDD + (j - slot * EDD);
                const double v = cval[t];
                int rank = 0;
                for (int i = 0; i < ncand; ++i) {
                    const int ji = cidx[i];
                    const int si = (ji >= EDD) ? 1 : 0;
                    const int di = eids[tok * 2 + si] * EDD + (ji - si * EDD);
                    const double vi = cval[i];
                    rank += (vi > v) || (vi == v && di < my_didx);
                }
                if (rank < need_s) {
                    sel_didx[nsel_s + rank] = my_didx;
                    sel_act[nsel_s + rank] = (float)v;
                }
            }
        }
        __syncthreads();
    }

    // fused decode: 8-wave k-split, 24B/lane/row, 4-deep load/FMA pipeline.
    const int total = total_s;
    const int wv = t >> 6;
    const int lane = t & 63;
    float accd[12];
#pragma unroll
    for (int i = 0; i < 12; ++i) accd[i] = 0.f;

    if (DEC16) {
        auto ldrow = [&](int k, float& a, ushort4& u0, ushort4& u1, ushort4& u2) {
            a = sel_act[k];
            const char* dr = (const char*)(dec16 + (size_t)sel_didx[k] * DD) + lane * 24;
            u0 = *reinterpret_cast<const ushort4*>(dr);
            u1 = *reinterpret_cast<const ushort4*>(dr + 8);
            u2 = *reinterpret_cast<const ushort4*>(dr + 16);
        };
        auto fmarow = [&](float a, ushort4 u0, ushort4 u1, ushort4 u2) {
            accd[0] += a * bf2f(u0.x);  accd[1]  += a * bf2f(u0.y);
            accd[2] += a * bf2f(u0.z);  accd[3]  += a * bf2f(u0.w);
            accd[4] += a * bf2f(u1.x);  accd[5]  += a * bf2f(u1.y);
            accd[6] += a * bf2f(u1.z);  accd[7]  += a * bf2f(u1.w);
            accd[8] += a * bf2f(u2.x);  accd[9]  += a * bf2f(u2.y);
            accd[10] += a * bf2f(u2.z); accd[11] += a * bf2f(u2.w);
        };
        int k = wv;
        for (; k + 24 < total; k += 32) {
            float a0, a1, a2, a3;
            ushort4 p00, p01, p02, p10, p11, p12, p20, p21, p22, p30, p31, p32;
            ldrow(k,      a0, p00, p01, p02);
            ldrow(k + 8,  a1, p10, p11, p12);
            ldrow(k + 16, a2, p20, p21, p22);
            ldrow(k + 24, a3, p30, p31, p32);
            fmarow(a0, p00, p01, p02);
            fmarow(a1, p10, p11, p12);
            fmarow(a2, p20, p21, p22);
            fmarow(a3, p30, p31, p32);
        }
        for (; k < total; k += 8) {
            float a; ushort4 q0, q1, q2;
            ldrow(k, a, q0, q1, q2);
            fmarow(a, q0, q1, q2);
        }
    } else {
        auto body = [&](int k) {
            const float a = sel_act[k];
            const float* dr = decoder + (size_t)sel_didx[k] * DD + lane * 12;
            const float4 f0 = *reinterpret_cast<const float4*>(dr);
            const float4 f1 = *reinterpret_cast<const float4*>(dr + 4);
            const float4 f2 = *reinterpret_cast<const float4*>(dr + 8);
            accd[0] += a * f0.x;  accd[1]  += a * f0.y;
            accd[2] += a * f0.z;  accd[3]  += a * f0.w;
            accd[4] += a * f1.x;  accd[5]  += a * f1.y;
            accd[6] += a * f1.z;  accd[7]  += a * f1.w;
            accd[8] += a * f2.x;  accd[9]  += a * f2.y;
            accd[10] += a * f2.z; accd[11] += a * f2.w;
        };
        int k = wv;
        for (; k + 8 < total; k += 16) { body(k); body(k + 8); }
        if (k < total) body(k);
    }

    // red overlays the arena — all reads of fv/cval are complete by here
#pragma unroll
    for (int i = 0; i < 12; ++i)
        red[wv * DD + lane * 12 + i] = accd[i];
    __syncthreads();
#pragma unroll
    for (int i = 0; i < 2; ++i) {
        const int j = t + 512 * i;
        if (j < DD) {
            float s = b_dec[j];
#pragma unroll
            for (int w = 0; w < 8; ++w) s += red[w * DD + j];
            out[(size_t)tok * DD + j] = s;
        }
    }
}

// sentinel fill if workspace is too small (diagnosable: absmax ~ 12345)
__global__ void k_sentinel(float* __restrict__ out, int n) {
    int i = blockIdx.x * blockDim.x + threadIdx.x;
    if (i < n) out[i] = 12345.0f;
}

extern "C" void kernel_launch(void* const* d_in, const int* in_sizes, int n_in,
                              void* d_out, int out_size, void* d_ws, size_t ws_size,
                              hipStream_t stream)
{
    (void)in_sizes; (void)n_in;
    const float* x        = (const float*)d_in[0];
    const float* gate_W   = (const float*)d_in[1];
    const float* gate_b   = (const float*)d_in[2];
    const float* b_gate   = (const float*)d_in[3];
    const float* b_dec    = (const float*)d_in[4];
    const float* expert_W = (const float*)d_in[5];
    const float* expert_b = (const float*)d_in[6];
    const float* decoder  = (const float*)d_in[7];
    float* out = (float*)d_out;

    char* ws = (char*)d_ws;
    const size_t off_counts0 = 64;
    const size_t off_blkcnt = 256;
    const size_t off_blkoff = off_blkcnt + (size_t)NE * K1BLK * 4;
    const size_t off_rnk    = off_blkoff + (size_t)NE * K1BLK * 4;
    const size_t off_eids   = off_rnk    + (size_t)NB * 2 * 4;
    const size_t off_entw   = off_eids   + (size_t)NB * 2 * 4;
    const size_t off_lists  = off_entw   + (size_t)NB * 2 * 8;
    const size_t off_fbuf   = off_lists  + (size_t)NE * MAXT * 4;
    const size_t off_xbf    = off_fbuf   + (size_t)NB * 2 * EDD * 2;
    const size_t off_bc0    = off_xbf    + (size_t)NB * DD * 2;
    const size_t off_bo0    = off_bc0    + (size_t)NE * K1BLK * 4;
    const size_t off_rnk0   = off_bo0    + (size_t)NE * K1BLK * 4;
    const size_t off_tokord = off_rnk0   + (size_t)NB * 4;
    const size_t base_end   = off_tokord + (size_t)NB * 4;           // ~64.4 MB
    const size_t WSZ        = (size_t)NE * EDD * DD * 2;             // 37.75 MB

    if (ws_size < base_end) {
        k_sentinel<<<(out_size + 255) / 256, 256, 0, stream>>>(out, out_size);
        return;
    }
    size_t off = base_end;
    const bool have_w = (ws_size >= off + WSZ);
    unsigned short* wbf = have_w ? (unsigned short*)(ws + off) : nullptr;
    if (have_w) off += WSZ;
    const bool have_d = (ws_size >= off + WSZ);
    unsigned short* dec16v = have_d ? (unsigned short*)(ws + off) : nullptr;

    int*            counts  = (int*)ws;
    int*            counts0 = (int*)(ws + off_counts0);
    int*            blk_cnt = (int*)(ws + off_blkcnt);
    int*            blk_off = (int*)(ws + off_blkoff);
    int*            rnk     = (int*)(ws + off_rnk);
    int*            eids    = (int*)(ws + off_eids);
    double*         entw    = (double*)(ws + off_entw);
    int*            lists   = (int*)(ws + off_lists);
    unsigned short* fbuf    = (unsigned short*)(ws + off_fbuf);
    unsigned short* xbf     = (unsigned short*)(ws + off_xbf);
    int*            blk_cnt0= (int*)(ws + off_bc0);
    int*            blk_off0= (int*)(ws + off_bo0);
    int*            rnk0    = (int*)(ws + off_rnk0);
    int*            tokord  = (int*)(ws + off_tokord);

    hipMemsetAsync(counts, 0, 128, stream);

    k0_prep_x<<<(NB * DD / 4) / 256, 256, 0, stream>>>(x, b_dec, xbf);
    const int n4blocks = (NE * EDD * DD / 4) / 256;   // 18432
    if (have_w)
        k0_cvt_bf<<<n4blocks, 256, 0, stream>>>(expert_W, wbf);
    if (have_d)
        k0_cvt_bf<<<n4blocks, 256, 0, stream>>>(decoder, dec16v);

    k1_gate<<<K1BLK, 256, 0, stream>>>(x, gate_W, gate_b, b_gate, eids, entw,
                                       rnk, blk_cnt, rnk0, blk_cnt0);
    k1_scan<<<2 * NE, 256, 0, stream>>>(blk_cnt, blk_off, counts,
                                        blk_cnt0, blk_off0, counts0);
    k1_scatter<<<NB * 2 / 256, 256, 0, stream>>>(eids, rnk, blk_off, lists,
                                                 rnk0, blk_off0, counts0, tokord);

    dim3 g2(EDD / 128, MAXT / 128, NE);   // (ntile=12, mtile=64, e=16), early-exit
    if (have_w)
        k2_encode<true><<<g2, 256, 0, stream>>>(xbf, wbf, expert_W, expert_b,
                                                counts, lists, entw, fbuf);
    else
        k2_encode<false><<<g2, 256, 0, stream>>>(xbf, wbf, expert_W, expert_b,
                                                 counts, lists, entw, fbuf);

    if (have_d)
        k3_topk_decode<1><<<NB, 512, 0, stream>>>(x, b_dec, expert_W, expert_b, eids,
                                                  entw, fbuf, decoder, dec16v, tokord, out);
    else
        k3_topk_decode<0><<<NB, 512, 0, stream>>>(x, b_dec, expert_W, expert_b, eids,
                                                  entw, fbuf, decoder, dec16v, tokord, out);
}

// Round 9
// 348.404 us; speedup vs baseline: 1.2674x; 1.1088x over previous
//
#include <hip/hip_runtime.h>
#include <hip/hip_fp16.h>
#include <cstdint>
#include <cstddef>

#define NB    8192
#define DD    768
#define NE    16
#define EDD   1536
#define KTOP  100
#define MAXT  8192
#define CAND_MAX 256
#define K1BLK 2048
#define NSTEP 12
#define BKBYTES 128      // 64 k * 2B
#define CONF_ULP 21
#define BAND_ULP 20

typedef __attribute__((ext_vector_type(4))) float f32x4;
typedef __attribute__((ext_vector_type(8))) short bf16x8;

#define VMCNT8() asm volatile("s_waitcnt vmcnt(8)" ::: "memory")
#define VMCNT4() asm volatile("s_waitcnt vmcnt(4)" ::: "memory")
#define VMCNT0() asm volatile("s_waitcnt vmcnt(0)" ::: "memory")

__device__ __forceinline__ unsigned short f2bf(float v) {
    unsigned int u = __float_as_uint(v);
    u += 0x7FFFu + ((u >> 16) & 1u);   // RNE to bf16
    return (unsigned short)(u >> 16);
}
__device__ __forceinline__ float bf2f(unsigned short h) {
    return __uint_as_float(((unsigned int)h) << 16);
}
__device__ __forceinline__ unsigned short f2h_bits(float v) {
    return __half_as_ushort(__float2half(v));
}
__device__ __forceinline__ float h2f_bits(unsigned short b) {
    return __half2float(__ushort_as_half(b));
}
__device__ __forceinline__ void async16(const void* g, void* l) {
    __builtin_amdgcn_global_load_lds(
        (const __attribute__((address_space(1))) unsigned int*)g,
        (__attribute__((address_space(3))) unsigned int*)l, 16, 0, 0);
}

// ---------------------------------------------------------------- K0: convert
__global__ __launch_bounds__(256) void k0_cvt_bf(
    const float* __restrict__ src, unsigned short* __restrict__ dst)
{
    const int i = blockIdx.x * 256 + threadIdx.x;
    const float4 v = reinterpret_cast<const float4*>(src)[i];
    ushort4 h;
    h.x = f2bf(v.x); h.y = f2bf(v.y); h.z = f2bf(v.z); h.w = f2bf(v.w);
    reinterpret_cast<ushort4*>(dst)[i] = h;
}

// ---------------------------------------------------------------- K1a: gate (+ fused xbf emit)
__global__ __launch_bounds__(256) void k1_gate(
    const float* __restrict__ x, const float* __restrict__ gate_W,
    const float* __restrict__ gate_b, const float* __restrict__ b_gate,
    const float* __restrict__ b_dec, unsigned short* __restrict__ xbf,
    int* __restrict__ eids, double* __restrict__ entw,
    int* __restrict__ rnk, int* __restrict__ blk_cnt,
    int* __restrict__ rnk0, int* __restrict__ blk_cnt0)
{
    __shared__ int cnt[NE];
    __shared__ int cnt0[NE];
    const int wid  = threadIdx.x >> 6;
    const int lane = threadIdx.x & 63;
    const int blk  = blockIdx.x;
    const int tok  = blk * 4 + wid;

    if (threadIdx.x < NE) { cnt[threadIdx.x] = 0; cnt0[threadIdx.x] = 0; }
    __syncthreads();

    double xv[12];
#pragma unroll
    for (int j = 0; j < 12; ++j) {
        const int k = j * 64 + lane;
        const float xr = x[(size_t)tok * DD + k];
        xv[j] = (double)xr - (double)b_gate[k];
        xbf[(size_t)tok * DD + k] = f2bf(xr - b_dec[k]);   // fused k0_prep_x
    }

    double myLogit = -1.0e300;
    for (int e = 0; e < NE; ++e) {
        double d = 0.0;
#pragma unroll
        for (int j = 0; j < 12; ++j)
            d += xv[j] * (double)gate_W[e * DD + j * 64 + lane];
#pragma unroll
        for (int off = 32; off > 0; off >>= 1)
            d += __shfl_xor(d, off);
        if (lane == e) myLogit = d + (double)gate_b[e];
    }

    double m = myLogit;
#pragma unroll
    for (int off = 8; off > 0; off >>= 1) {
        double o = __shfl_xor(m, off); m = (o > m) ? o : m;
    }
    double p = exp(myLogit - m);
    double ssum = p;
#pragma unroll
    for (int off = 8; off > 0; off >>= 1) ssum += __shfl_xor(ssum, off);
    const double score = p / ssum;

    const bool lt16 = (lane < NE);
    double m1 = score;
#pragma unroll
    for (int off = 8; off > 0; off >>= 1) {
        double o = __shfl_xor(m1, off); m1 = (o > m1) ? o : m1;
    }
    unsigned long long b0 = __ballot(lt16 && (score == m1));
    const int i0 = __ffsll(b0) - 1;
    double sc2 = (lane == i0) ? -1.0 : score;
    double m2 = sc2;
#pragma unroll
    for (int off = 8; off > 0; off >>= 1) {
        double o = __shfl_xor(m2, off); m2 = (o > m2) ? o : m2;
    }
    unsigned long long b1 = __ballot(lt16 && (sc2 == m2));
    const int i1 = __ffsll(b1) - 1;

    if (lane == 0) {
        const double w0 = 1.0 / (1.0 + exp(m2 - m1));
        const double w1 = 1.0 - w0;
        eids[tok * 2 + 0] = i0;
        eids[tok * 2 + 1] = i1;
        entw[tok * 2 + 0] = w0;
        entw[tok * 2 + 1] = w1;
        rnk[tok * 2 + 0] = atomicAdd(&cnt[i0], 1);
        rnk[tok * 2 + 1] = atomicAdd(&cnt[i1], 1);
        rnk0[tok] = atomicAdd(&cnt0[i0], 1);
    }
    __syncthreads();
    if (threadIdx.x < NE) {
        blk_cnt [threadIdx.x * K1BLK + blk] = cnt [threadIdx.x];
        blk_cnt0[threadIdx.x * K1BLK + blk] = cnt0[threadIdx.x];
    }
}

// ------------------------------------------- K1b: scan (32 blocks: 16 entry-lists, 16 slot0-order)
__global__ __launch_bounds__(256) void k1_scan(
    const int* __restrict__ bc,  int* __restrict__ bo,  int* __restrict__ counts,
    const int* __restrict__ bc0, int* __restrict__ bo0, int* __restrict__ counts0)
{
    __shared__ int tsum[256];
    const int g = blockIdx.x;
    const int e = g & 15;
    const int* src = (g >= NE) ? bc0 : bc;
    int* dst       = (g >= NE) ? bo0 : bo;
    int* cn        = (g >= NE) ? counts0 : counts;
    const int t = threadIdx.x;
    int loc[8]; int s = 0;
#pragma unroll
    for (int i = 0; i < 8; ++i) { loc[i] = s; s += src[e * K1BLK + t * 8 + i]; }
    tsum[t] = s;
    __syncthreads();
    for (int off = 1; off < 256; off <<= 1) {
        const int u = (t >= off) ? tsum[t - off] : 0;
        __syncthreads();
        tsum[t] += u;
        __syncthreads();
    }
    const int excl = tsum[t] - s;
#pragma unroll
    for (int i = 0; i < 8; ++i) dst[e * K1BLK + t * 8 + i] = excl + loc[i];
    if (t == 255) cn[e] = tsum[255];
}

// ---------------------------------------------------------------- K1c: scatter
__global__ __launch_bounds__(256) void k1_scatter(
    const int* __restrict__ eids, const int* __restrict__ rnk,
    const int* __restrict__ blk_off, int* __restrict__ lists,
    const int* __restrict__ rnk0, const int* __restrict__ blk_off0,
    const int* __restrict__ counts0, int* __restrict__ tokord)
{
    const int i = blockIdx.x * 256 + threadIdx.x;   // 16384 entries
    const int e = eids[i];
    const int blk = i >> 3;
    lists[e * MAXT + blk_off[e * K1BLK + blk] + rnk[i]] = i;
    if (!(i & 1)) {
        const int tok = i >> 1;
        int base0 = 0;
#pragma unroll
        for (int e2 = 0; e2 < NE; ++e2) base0 += (e2 < e) ? counts0[e2] : 0;
        tokord[base0 + blk_off0[e * K1BLK + blk] + rnk0[tok]] = tok;
    }
}

// ------------------------------------------------- K2: grouped expert GEMM
// pure-bf16, double-buffered LDS, all-async staging, counted vmcnt (T3+T4).
// XCD-chunked expert-contiguous grid: each XCD owns 2 experts -> its W-slice
// (2.36 MB bf16) stays resident in that XCD's private L2.
template<bool WBF>
__global__ __launch_bounds__(256, 2) void k2_encode(
    const unsigned short* __restrict__ xbf,
    const unsigned short* __restrict__ wbf,
    const float* __restrict__ expert_W,
    const float* __restrict__ expert_b,
    const int* __restrict__ counts, const int* __restrict__ lists,
    const double* __restrict__ entw, unsigned short* __restrict__ fbuf)
{
    // remap: 12288 blocks; xcd = wg&7 gets contiguous 1536 = 2 experts.
    const int wg  = blockIdx.x;
    const int gw  = (wg & 7) * 1536 + (wg >> 3);
    const int e   = gw / 768;
    const int rem = gw % 768;
    const int cnt = counts[e];
    const int mbase = (rem / 12) * 128;        // mtile-major, ntile fastest
    if (mbase >= cnt) return;
    const int rows = min(128, cnt - mbase);
    const int nbase = (rem % 12) * 128;

    __shared__ char smem[65536];   // 2 buffers x (A 16KB | B 16KB)

    const int t = threadIdx.x;
    const int lane = t & 63;
    const int wid = t >> 6;
    const int wm = wid >> 1, wn = wid & 1;
    const int l15 = lane & 15, q = lane >> 4;
    const int rl = lane >> 3;          // row-within-8 for async staging
    const int cg = lane & 7;           // 16B chunk index
    const int xorc = (cg ^ rl) << 4;   // inverse-swizzled source chunk byte

    size_t asrc[4];
#pragma unroll
    for (int j = 0; j < 4; ++j) {
        const int r = (wid * 4 + j) * 8 + rl;
        const int rr = (r < rows) ? r : 0;
        const int tok = lists[e * MAXT + mbase + rr] >> 1;
        asrc[j] = (size_t)tok * (DD * 2) + xorc;
    }
    size_t bsrc[4];
#pragma unroll
    for (int j = 0; j < 4; ++j) {
        const int r = (wid * 4 + j) * 8 + rl;
        bsrc[j] = ((size_t)(e * EDD + nbase + r)) * (DD * 2) + xorc;
    }
    const int kq = t & 15, rg = t >> 4;   // !WBF B-convert map

    f32x4 acc[4][4];
#pragma unroll
    for (int a = 0; a < 4; ++a)
#pragma unroll
        for (int b = 0; b < 4; ++b)
            acc[a][b] = f32x4{0.f, 0.f, 0.f, 0.f};

    auto stageA = [&](int s, char* buf) {
#pragma unroll
        for (int j = 0; j < 4; ++j)
            async16((const char*)xbf + asrc[j] + (size_t)s * BKBYTES,
                    buf + ((wid * 4 + j) << 10));
    };
    auto stageB_async = [&](int s, char* buf) {
#pragma unroll
        for (int j = 0; j < 4; ++j)
            async16((const char*)wbf + bsrc[j] + (size_t)s * BKBYTES,
                    buf + 16384 + ((wid * 4 + j) << 10));
    };
    auto stageB_cvt = [&](int s, char* buf) {
#pragma unroll
        for (int j = 0; j < 8; ++j) {
            const int r = rg * 8 + j;
            const float4 bv = *reinterpret_cast<const float4*>(
                expert_W + ((size_t)e * EDD + nbase + r) * DD + s * 64 + kq * 4);
            ushort4 b4;
            b4.x = f2bf(bv.x); b4.y = f2bf(bv.y); b4.z = f2bf(bv.z); b4.w = f2bf(bv.w);
            *reinterpret_cast<ushort4*>(
                buf + 16384 + ((r * 128 + kq * 8) ^ ((r & 7) << 4))) = b4;
        }
    };
    auto compute = [&](char* buf) {
#pragma unroll
        for (int ks = 0; ks < 2; ++ks) {
            bf16x8 ah[4], bh[4];
#pragma unroll
            for (int fm = 0; fm < 4; ++fm) {
                const int row = wm * 64 + fm * 16 + l15;
                ah[fm] = *reinterpret_cast<const bf16x8*>(
                    buf + row * 128 + ((ks * 64 + q * 16) ^ ((row & 7) << 4)));
            }
#pragma unroll
            for (int fn = 0; fn < 4; ++fn) {
                const int row = wn * 64 + fn * 16 + l15;
                bh[fn] = *reinterpret_cast<const bf16x8*>(
                    buf + 16384 + row * 128 + ((ks * 64 + q * 16) ^ ((row & 7) << 4)));
            }
#pragma unroll
            for (int fm = 0; fm < 4; ++fm)
#pragma unroll
                for (int fn = 0; fn < 4; ++fn)
                    acc[fm][fn] = __builtin_amdgcn_mfma_f32_16x16x32_bf16(
                        ah[fm], bh[fn], acc[fm][fn], 0, 0, 0);
        }
    };

    // prologue: stage tile 0 into buffer 0
    if constexpr (WBF) {
        stageA(0, smem);
        stageB_async(0, smem);
    } else {
        stageB_cvt(0, smem);
        stageA(0, smem);
    }

    for (int s = 0; s < NSTEP; ++s) {
        char* cur = smem + ((s & 1) << 15);
        char* nxt = smem + (((s & 1) ^ 1) << 15);
        if (s + 1 < NSTEP) {
            if constexpr (WBF) {
                stageA(s + 1, nxt);
                stageB_async(s + 1, nxt);
                VMCNT8();              // retire tile s, keep tile s+1 in flight
            } else {
                stageB_cvt(s + 1, nxt);
                stageA(s + 1, nxt);
                VMCNT4();
            }
        } else {
            VMCNT0();
        }
        __syncthreads();
        compute(cur);
        __syncthreads();
    }

    // epilogue: C/D layout col=lane&15, row=(lane>>4)*4+reg; bias+relu+renorm; f16 out
#pragma unroll
    for (int fm = 0; fm < 4; ++fm) {
#pragma unroll
        for (int r = 0; r < 4; ++r) {
            const int ml = wm * 64 + fm * 16 + q * 4 + r;
            if (ml >= rows) continue;
            const int ent = lists[e * MAXT + mbase + ml];
            const float ren = (float)entw[ent];
            unsigned short* fout = fbuf + (size_t)ent * EDD + nbase;
#pragma unroll
            for (int fn = 0; fn < 4; ++fn) {
                const int nl = wn * 64 + fn * 16 + l15;
                float v = acc[fm][fn][r] + expert_b[e * EDD + nbase + nl];
                v = fmaxf(v, 0.f) * ren;
                fout[nl] = f2h_bits(v);
            }
        }
    }
}

// --------------------------- K3: per-token exact top-100 + fused decode
// 256 threads (4 waves, max independent blocks/CU); parallel suffix-scan
// radix thresholds; expert-major token order + XCD-chunked dispatch.
template<int DEC16>
__global__ __launch_bounds__(256) void k3_topk_decode(
    const float* __restrict__ x, const float* __restrict__ b_dec,
    const float* __restrict__ expert_W, const float* __restrict__ expert_b,
    const int* __restrict__ eids, const double* __restrict__ entw,
    const unsigned short* __restrict__ fbuf,
    const float* __restrict__ decoder, const unsigned short* __restrict__ dec16,
    const int* __restrict__ tokord, float* __restrict__ out)
{
    const int bid = blockIdx.x;
    const int tok = tokord[(bid & 7) * (NB / 8) + (bid >> 3)];
    const int t = threadIdx.x;

    // arena overlay: [fv 6144 | hist 1024 | cidx 1024 | cval 2048] before decode;
    // red[4*768 floats = 12288] after selection (all earlier arrays dead then).
    __shared__ __align__(16) char arena[12288];
    unsigned short* fv   = (unsigned short*)arena;
    unsigned int*   hist = (unsigned int*)(arena + 6144);
    int*            cidx = (int*)(arena + 7168);
    double*         cval = (double*)(arena + 8192);
    float*          red  = (float*)arena;
    __shared__ unsigned int sc[256];
    __shared__ int hb_s, T_s, rem_s, tz_s, nsel_s, ncand_s, total_s, need_s;
    __shared__ int   sel_didx[KTOP];
    __shared__ float sel_act[KTOP];

    const unsigned int* frow = reinterpret_cast<const unsigned int*>(fbuf + (size_t)tok * 2 * EDD);
#pragma unroll
    for (int i = 0; i < 6; ++i)
        reinterpret_cast<unsigned int*>(fv)[t + 256 * i] = frow[t + 256 * i];
    if (t == 0) { tz_s = 0; nsel_s = 0; ncand_s = 0; }
    hist[t] = 0u;
    __syncthreads();

    // pass 1: top byte of f16 bits (all values >= 0)
#pragma unroll
    for (int i = 0; i < 12; ++i) {
        const unsigned int u = fv[t + 256 * i];
        if (u) atomicAdd(&hist[u >> 8], 1u);
    }
    __syncthreads();
    // parallel suffix scan: sc[v] = sum_{u>=v} hist[u]
    sc[t] = hist[t];
    __syncthreads();
    for (int off = 1; off < 256; off <<= 1) {
        const unsigned int v2 = (t < 256 - off) ? sc[t + off] : 0u;
        __syncthreads();
        sc[t] += v2;
        __syncthreads();
    }
    {
        const unsigned int above = (t == 255) ? 0u : sc[t + 1];
        if (sc[t] >= KTOP && above < KTOP) { hb_s = t; rem_s = KTOP - (int)above; }
        if (t == 0 && sc[0] < KTOP) tz_s = 1;
    }
    __syncthreads();

    if (!tz_s) {
        hist[t] = 0u;
        __syncthreads();
        const unsigned int hb = (unsigned int)hb_s;
#pragma unroll
        for (int i = 0; i < 12; ++i) {
            const unsigned int u = fv[t + 256 * i];
            if (u && (u >> 8) == hb) atomicAdd(&hist[u & 255u], 1u);
        }
        __syncthreads();
        sc[t] = hist[t];
        __syncthreads();
        for (int off = 1; off < 256; off <<= 1) {
            const unsigned int v2 = (t < 256 - off) ? sc[t + off] : 0u;
            __syncthreads();
            sc[t] += v2;
            __syncthreads();
        }
        {
            const unsigned int rem = (unsigned int)rem_s;
            const unsigned int above = (t == 255) ? 0u : sc[t + 1];
            if (sc[t] >= rem && above < rem) T_s = (hb_s << 8) | t;
        }
        __syncthreads();
    }

    if (tz_s) {
        // fewer than 100 positives: take them all (rest are exact zeros)
#pragma unroll
        for (int i = 0; i < 12; ++i) {
            const int j = t + 256 * i;
            const unsigned int u = fv[j];
            if (u) {
                const int p = atomicAdd(&nsel_s, 1);
                const int slot = (j >= EDD) ? 1 : 0;
                const int n = j - slot * EDD;
                sel_didx[p] = eids[tok * 2 + slot] * EDD + n;
                sel_act[p] = h2f_bits((unsigned short)u);
            }
        }
        __syncthreads();
        if (t == 0) total_s = nsel_s;
        __syncthreads();
    } else {
        const int T = T_s;
#pragma unroll
        for (int i = 0; i < 12; ++i) {
            const int j = t + 256 * i;
            const unsigned int u = fv[j];
            if ((int)u >= T + CONF_ULP) {
                const int p = atomicAdd(&nsel_s, 1);
                const int slot = (j >= EDD) ? 1 : 0;
                const int n = j - slot * EDD;
                sel_didx[p] = eids[tok * 2 + slot] * EDD + n;
                sel_act[p] = h2f_bits((unsigned short)u);
            } else if (u != 0u && (int)u + BAND_ULP >= T) {
                const int c = atomicAdd(&ncand_s, 1);
                if (c < CAND_MAX) cidx[c] = j;
            }
        }
        __syncthreads();

        // fp64 re-evaluation of candidates, one wave per candidate (4 waves)
        {
            const int ncand = min(ncand_s, CAND_MAX);
            const int wv = t >> 6, lane = t & 63;
            for (int c = wv; c < ncand; c += 4) {
                const int j = cidx[c];
                const int slot = (j >= EDD) ? 1 : 0;
                const int n = j - slot * EDD;
                const int ee = eids[tok * 2 + slot];
                const float* wr = expert_W + ((size_t)ee * EDD + n) * DD;
                const float* xr = x + (size_t)tok * DD;
                double d = 0.0;
#pragma unroll
                for (int jj = 0; jj < 12; ++jj) {
                    const int k = jj * 64 + lane;
                    d += ((double)xr[k] - (double)b_dec[k]) * (double)wr[k];
                }
#pragma unroll
                for (int off = 32; off > 0; off >>= 1) d += __shfl_xor(d, off);
                if (lane == 0) {
                    double z = d + (double)expert_b[ee * EDD + n];
                    if (z < 0.0) z = 0.0;
                    cval[c] = z * entw[tok * 2 + slot];
                }
            }
        }
        __syncthreads();
        if (t == 0) {
            const int ncand = min(ncand_s, CAND_MAX);
            int need = KTOP - nsel_s;
            if (need > ncand) need = ncand;
            if (need < 0) need = 0;
            need_s = need;
            total_s = nsel_s + need;
        }
        __syncthreads();

        // parallel rank-based selection among candidates (value desc, dict idx asc)
        {
            const int ncand = min(ncand_s, CAND_MAX);
            if (t < ncand) {
                const int j = cidx[t];
                const int slot = (j >= EDD) ? 1 : 0;
                const int my_didx = eids[tok * 2 + slot] * EDD + (j - slot * EDD);
                const double v = cval[t];
                int rank = 0;
                for (int i = 0; i < ncand; ++i) {
                    const int ji = cidx[i];
                    const int si = (ji >= EDD) ? 1 : 0;
                    const int di = eids[tok * 2 + si] * EDD + (ji - si * EDD);
                    const double vi = cval[i];
                    rank += (vi > v) || (vi == v && di < my_didx);
                }
                if (rank < need_s) {
                    sel_didx[nsel_s + rank] = my_didx;
                    sel_act[nsel_s + rank] = (float)v;
                }
            }
        }
        __syncthreads();
    }

    // fused decode: 4-wave k-split, 24B/lane/row, 4-deep load/FMA pipeline.
    const int total = total_s;
    const int wv = t >> 6;
    const int lane = t & 63;
    float accd[12];
#pragma unroll
    for (int i = 0; i < 12; ++i) accd[i] = 0.f;

    if (DEC16) {
        auto ldrow = [&](int k, float& a, ushort4& u0, ushort4& u1, ushort4& u2) {
            a = sel_act[k];
            const char* dr = (const char*)(dec16 + (size_t)sel_didx[k] * DD) + lane * 24;
            u0 = *reinterpret_cast<const ushort4*>(dr);
            u1 = *reinterpret_cast<const ushort4*>(dr + 8);
            u2 = *reinterpret_cast<const ushort4*>(dr + 16);
        };
        auto fmarow = [&](float a, ushort4 u0, ushort4 u1, ushort4 u2) {
            accd[0] += a * bf2f(u0.x);  accd[1]  += a * bf2f(u0.y);
            accd[2] += a * bf2f(u0.z);  accd[3]  += a * bf2f(u0.w);
            accd[4] += a * bf2f(u1.x);  accd[5]  += a * bf2f(u1.y);
            accd[6] += a * bf2f(u1.z);  accd[7]  += a * bf2f(u1.w);
            accd[8] += a * bf2f(u2.x);  accd[9]  += a * bf2f(u2.y);
            accd[10] += a * bf2f(u2.z); accd[11] += a * bf2f(u2.w);
        };
        int k = wv;
        for (; k + 12 < total; k += 16) {
            float a0, a1, a2, a3;
            ushort4 p00, p01, p02, p10, p11, p12, p20, p21, p22, p30, p31, p32;
            ldrow(k,      a0, p00, p01, p02);
            ldrow(k + 4,  a1, p10, p11, p12);
            ldrow(k + 8,  a2, p20, p21, p22);
            ldrow(k + 12, a3, p30, p31, p32);
            fmarow(a0, p00, p01, p02);
            fmarow(a1, p10, p11, p12);
            fmarow(a2, p20, p21, p22);
            fmarow(a3, p30, p31, p32);
        }
        for (; k < total; k += 4) {
            float a; ushort4 q0, q1, q2;
            ldrow(k, a, q0, q1, q2);
            fmarow(a, q0, q1, q2);
        }
    } else {
        auto body = [&](int k) {
            const float a = sel_act[k];
            const float* dr = decoder + (size_t)sel_didx[k] * DD + lane * 12;
            const float4 f0 = *reinterpret_cast<const float4*>(dr);
            const float4 f1 = *reinterpret_cast<const float4*>(dr + 4);
            const float4 f2 = *reinterpret_cast<const float4*>(dr + 8);
            accd[0] += a * f0.x;  accd[1]  += a * f0.y;
            accd[2] += a * f0.z;  accd[3]  += a * f0.w;
            accd[4] += a * f1.x;  accd[5]  += a * f1.y;
            accd[6] += a * f1.z;  accd[7]  += a * f1.w;
            accd[8] += a * f2.x;  accd[9]  += a * f2.y;
            accd[10] += a * f2.z; accd[11] += a * f2.w;
        };
        int k = wv;
        for (; k + 4 < total; k += 8) { body(k); body(k + 4); }
        if (k < total) body(k);
    }

    // red overlays the arena — all reads of fv/cval are complete by here
#pragma unroll
    for (int i = 0; i < 12; ++i)
        red[wv * DD + lane * 12 + i] = accd[i];
    __syncthreads();
#pragma unroll
    for (int i = 0; i < 3; ++i) {
        const int j = t + 256 * i;
        out[(size_t)tok * DD + j] =
            red[j] + red[DD + j] + red[2 * DD + j] + red[3 * DD + j] + b_dec[j];
    }
}

// sentinel fill if workspace is too small (diagnosable: absmax ~ 12345)
__global__ void k_sentinel(float* __restrict__ out, int n) {
    int i = blockIdx.x * blockDim.x + threadIdx.x;
    if (i < n) out[i] = 12345.0f;
}

extern "C" void kernel_launch(void* const* d_in, const int* in_sizes, int n_in,
                              void* d_out, int out_size, void* d_ws, size_t ws_size,
                              hipStream_t stream)
{
    (void)in_sizes; (void)n_in;
    const float* x        = (const float*)d_in[0];
    const float* gate_W   = (const float*)d_in[1];
    const float* gate_b   = (const float*)d_in[2];
    const float* b_gate   = (const float*)d_in[3];
    const float* b_dec    = (const float*)d_in[4];
    const float* expert_W = (const float*)d_in[5];
    const float* expert_b = (const float*)d_in[6];
    const float* decoder  = (const float*)d_in[7];
    float* out = (float*)d_out;

    char* ws = (char*)d_ws;
    const size_t off_counts0 = 64;
    const size_t off_blkcnt = 256;
    const size_t off_blkoff = off_blkcnt + (size_t)NE * K1BLK * 4;
    const size_t off_rnk    = off_blkoff + (size_t)NE * K1BLK * 4;
    const size_t off_eids   = off_rnk    + (size_t)NB * 2 * 4;
    const size_t off_entw   = off_eids   + (size_t)NB * 2 * 4;
    const size_t off_lists  = off_entw   + (size_t)NB * 2 * 8;
    const size_t off_fbuf   = off_lists  + (size_t)NE * MAXT * 4;
    const size_t off_xbf    = off_fbuf   + (size_t)NB * 2 * EDD * 2;
    const size_t off_bc0    = off_xbf    + (size_t)NB * DD * 2;
    const size_t off_bo0    = off_bc0    + (size_t)NE * K1BLK * 4;
    const size_t off_rnk0   = off_bo0    + (size_t)NE * K1BLK * 4;
    const size_t off_tokord = off_rnk0   + (size_t)NB * 4;
    const size_t base_end   = off_tokord + (size_t)NB * 4;           // ~64.4 MB
    const size_t WSZ        = (size_t)NE * EDD * DD * 2;             // 37.75 MB

    if (ws_size < base_end) {
        k_sentinel<<<(out_size + 255) / 256, 256, 0, stream>>>(out, out_size);
        return;
    }
    size_t off = base_end;
    const bool have_w = (ws_size >= off + WSZ);
    unsigned short* wbf = have_w ? (unsigned short*)(ws + off) : nullptr;
    if (have_w) off += WSZ;
    const bool have_d = (ws_size >= off + WSZ);
    unsigned short* dec16v = have_d ? (unsigned short*)(ws + off) : nullptr;

    int*            counts  = (int*)ws;
    int*            counts0 = (int*)(ws + off_counts0);
    int*            blk_cnt = (int*)(ws + off_blkcnt);
    int*            blk_off = (int*)(ws + off_blkoff);
    int*            rnk     = (int*)(ws + off_rnk);
    int*            eids    = (int*)(ws + off_eids);
    double*         entw    = (double*)(ws + off_entw);
    int*            lists   = (int*)(ws + off_lists);
    unsigned short* fbuf    = (unsigned short*)(ws + off_fbuf);
    unsigned short* xbf     = (unsigned short*)(ws + off_xbf);
    int*            blk_cnt0= (int*)(ws + off_bc0);
    int*            blk_off0= (int*)(ws + off_bo0);
    int*            rnk0    = (int*)(ws + off_rnk0);
    int*            tokord  = (int*)(ws + off_tokord);

    hipMemsetAsync(counts, 0, 128, stream);

    const int n4blocks = (NE * EDD * DD / 4) / 256;   // 18432
    if (have_w)
        k0_cvt_bf<<<n4blocks, 256, 0, stream>>>(expert_W, wbf);
    if (have_d)
        k0_cvt_bf<<<n4blocks, 256, 0, stream>>>(decoder, dec16v);

    k1_gate<<<K1BLK, 256, 0, stream>>>(x, gate_W, gate_b, b_gate, b_dec, xbf,
                                       eids, entw, rnk, blk_cnt, rnk0, blk_cnt0);
    k1_scan<<<2 * NE, 256, 0, stream>>>(blk_cnt, blk_off, counts,
                                        blk_cnt0, blk_off0, counts0);
    k1_scatter<<<NB * 2 / 256, 256, 0, stream>>>(eids, rnk, blk_off, lists,
                                                 rnk0, blk_off0, counts0, tokord);

    if (have_w)
        k2_encode<true><<<12288, 256, 0, stream>>>(xbf, wbf, expert_W, expert_b,
                                                   counts, lists, entw, fbuf);
    else
        k2_encode<false><<<12288, 256, 0, stream>>>(xbf, wbf, expert_W, expert_b,
                                                    counts, lists, entw, fbuf);

    if (have_d)
        k3_topk_decode<1><<<NB, 256, 0, stream>>>(x, b_dec, expert_W, expert_b, eids,
                                                  entw, fbuf, decoder, dec16v, tokord, out);
    else
        k3_topk_decode<0><<<NB, 256, 0, stream>>>(x, b_dec, expert_W, expert_b, eids,
                                                  entw, fbuf, decoder, dec16v, tokord, out);
}

// Round 10
// 311.324 us; speedup vs baseline: 1.4183x; 1.1191x over previous
//
#include <hip/hip_runtime.h>
#include <hip/hip_fp16.h>
#include <cstdint>
#include <cstddef>

#define NB    8192
#define DD    768
#define NE    16
#define EDD   1536
#define KTOP  100
#define MAXT  8192
#define CAND_MAX 256
#define K1BLK 2048
#define NSTEP 12
#define BKBYTES 128      // 64 k * 2B
#define CONF_ULP 6
#define BAND_ULP 5

typedef __attribute__((ext_vector_type(4))) float f32x4;
typedef __attribute__((ext_vector_type(8))) _Float16 f16x8;

#define VMCNT8() asm volatile("s_waitcnt vmcnt(8)" ::: "memory")
#define VMCNT4() asm volatile("s_waitcnt vmcnt(4)" ::: "memory")
#define VMCNT0() asm volatile("s_waitcnt vmcnt(0)" ::: "memory")

__device__ __forceinline__ unsigned short f2bf(float v) {
    unsigned int u = __float_as_uint(v);
    u += 0x7FFFu + ((u >> 16) & 1u);   // RNE to bf16
    return (unsigned short)(u >> 16);
}
__device__ __forceinline__ float bf2f(unsigned short h) {
    return __uint_as_float(((unsigned int)h) << 16);
}
__device__ __forceinline__ unsigned short f2h_bits(float v) {
    return __half_as_ushort(__float2half(v));
}
__device__ __forceinline__ float h2f_bits(unsigned short b) {
    return __half2float(__ushort_as_half(b));
}
__device__ __forceinline__ void async16(const void* g, void* l) {
    __builtin_amdgcn_global_load_lds(
        (const __attribute__((address_space(1))) unsigned int*)g,
        (__attribute__((address_space(3))) unsigned int*)l, 16, 0, 0);
}

// ---------------------------------------------------------------- K0: converts
__global__ __launch_bounds__(256) void k0_cvt_bf(
    const float* __restrict__ src, unsigned short* __restrict__ dst)
{
    const int i = blockIdx.x * 256 + threadIdx.x;
    const float4 v = reinterpret_cast<const float4*>(src)[i];
    ushort4 h;
    h.x = f2bf(v.x); h.y = f2bf(v.y); h.z = f2bf(v.z); h.w = f2bf(v.w);
    reinterpret_cast<ushort4*>(dst)[i] = h;
}

__global__ __launch_bounds__(256) void k0_cvt_f16(
    const float* __restrict__ src, unsigned short* __restrict__ dst)
{
    const int i = blockIdx.x * 256 + threadIdx.x;
    const float4 v = reinterpret_cast<const float4*>(src)[i];
    ushort4 h;
    h.x = f2h_bits(v.x); h.y = f2h_bits(v.y); h.z = f2h_bits(v.z); h.w = f2h_bits(v.w);
    reinterpret_cast<ushort4*>(dst)[i] = h;
}

// ---------------------------------------------------------------- K1a: gate (+ fused xf16 emit)
__global__ __launch_bounds__(256) void k1_gate(
    const float* __restrict__ x, const float* __restrict__ gate_W,
    const float* __restrict__ gate_b, const float* __restrict__ b_gate,
    const float* __restrict__ b_dec, unsigned short* __restrict__ xf16,
    int* __restrict__ eids, double* __restrict__ entw,
    int* __restrict__ rnk, int* __restrict__ blk_cnt,
    int* __restrict__ rnk0, int* __restrict__ blk_cnt0)
{
    __shared__ int cnt[NE];
    __shared__ int cnt0[NE];
    const int wid  = threadIdx.x >> 6;
    const int lane = threadIdx.x & 63;
    const int blk  = blockIdx.x;
    const int tok  = blk * 4 + wid;

    if (threadIdx.x < NE) { cnt[threadIdx.x] = 0; cnt0[threadIdx.x] = 0; }
    __syncthreads();

    double xv[12];
#pragma unroll
    for (int j = 0; j < 12; ++j) {
        const int k = j * 64 + lane;
        const float xr = x[(size_t)tok * DD + k];
        xv[j] = (double)xr - (double)b_gate[k];
        xf16[(size_t)tok * DD + k] = f2h_bits(xr - b_dec[k]);   // fused prep_x (f16)
    }

    double myLogit = -1.0e300;
    for (int e = 0; e < NE; ++e) {
        double d = 0.0;
#pragma unroll
        for (int j = 0; j < 12; ++j)
            d += xv[j] * (double)gate_W[e * DD + j * 64 + lane];
#pragma unroll
        for (int off = 32; off > 0; off >>= 1)
            d += __shfl_xor(d, off);
        if (lane == e) myLogit = d + (double)gate_b[e];
    }

    double m = myLogit;
#pragma unroll
    for (int off = 8; off > 0; off >>= 1) {
        double o = __shfl_xor(m, off); m = (o > m) ? o : m;
    }
    double p = exp(myLogit - m);
    double ssum = p;
#pragma unroll
    for (int off = 8; off > 0; off >>= 1) ssum += __shfl_xor(ssum, off);
    const double score = p / ssum;

    const bool lt16 = (lane < NE);
    double m1 = score;
#pragma unroll
    for (int off = 8; off > 0; off >>= 1) {
        double o = __shfl_xor(m1, off); m1 = (o > m1) ? o : m1;
    }
    unsigned long long b0 = __ballot(lt16 && (score == m1));
    const int i0 = __ffsll(b0) - 1;
    double sc2 = (lane == i0) ? -1.0 : score;
    double m2 = sc2;
#pragma unroll
    for (int off = 8; off > 0; off >>= 1) {
        double o = __shfl_xor(m2, off); m2 = (o > m2) ? o : m2;
    }
    unsigned long long b1 = __ballot(lt16 && (sc2 == m2));
    const int i1 = __ffsll(b1) - 1;

    if (lane == 0) {
        const double w0 = 1.0 / (1.0 + exp(m2 - m1));
        const double w1 = 1.0 - w0;
        eids[tok * 2 + 0] = i0;
        eids[tok * 2 + 1] = i1;
        entw[tok * 2 + 0] = w0;
        entw[tok * 2 + 1] = w1;
        rnk[tok * 2 + 0] = atomicAdd(&cnt[i0], 1);
        rnk[tok * 2 + 1] = atomicAdd(&cnt[i1], 1);
        rnk0[tok] = atomicAdd(&cnt0[i0], 1);
    }
    __syncthreads();
    if (threadIdx.x < NE) {
        blk_cnt [threadIdx.x * K1BLK + blk] = cnt [threadIdx.x];
        blk_cnt0[threadIdx.x * K1BLK + blk] = cnt0[threadIdx.x];
    }
}

// ------------------------------------------- K1b: scan (32 blocks: 16 entry-lists, 16 slot0-order)
__global__ __launch_bounds__(256) void k1_scan(
    const int* __restrict__ bc,  int* __restrict__ bo,  int* __restrict__ counts,
    const int* __restrict__ bc0, int* __restrict__ bo0, int* __restrict__ counts0)
{
    __shared__ int tsum[256];
    const int g = blockIdx.x;
    const int e = g & 15;
    const int* src = (g >= NE) ? bc0 : bc;
    int* dst       = (g >= NE) ? bo0 : bo;
    int* cn        = (g >= NE) ? counts0 : counts;
    const int t = threadIdx.x;
    int loc[8]; int s = 0;
#pragma unroll
    for (int i = 0; i < 8; ++i) { loc[i] = s; s += src[e * K1BLK + t * 8 + i]; }
    tsum[t] = s;
    __syncthreads();
    for (int off = 1; off < 256; off <<= 1) {
        const int u = (t >= off) ? tsum[t - off] : 0;
        __syncthreads();
        tsum[t] += u;
        __syncthreads();
    }
    const int excl = tsum[t] - s;
#pragma unroll
    for (int i = 0; i < 8; ++i) dst[e * K1BLK + t * 8 + i] = excl + loc[i];
    if (t == 255) cn[e] = tsum[255];
}

// ---------------------------------------------------------------- K1c: scatter
__global__ __launch_bounds__(256) void k1_scatter(
    const int* __restrict__ eids, const int* __restrict__ rnk,
    const int* __restrict__ blk_off, int* __restrict__ lists,
    const int* __restrict__ rnk0, const int* __restrict__ blk_off0,
    const int* __restrict__ counts0, int* __restrict__ tokord)
{
    const int i = blockIdx.x * 256 + threadIdx.x;   // 16384 entries
    const int e = eids[i];
    const int blk = i >> 3;
    lists[e * MAXT + blk_off[e * K1BLK + blk] + rnk[i]] = i;
    if (!(i & 1)) {
        const int tok = i >> 1;
        int base0 = 0;
#pragma unroll
        for (int e2 = 0; e2 < NE; ++e2) base0 += (e2 < e) ? counts0[e2] : 0;
        tokord[base0 + blk_off0[e * K1BLK + blk] + rnk0[tok]] = tok;
    }
}

// ------------------------------------------------- K2: grouped expert GEMM
// pure-f16, double-buffered LDS, all-async staging, counted vmcnt (T3+T4).
// XCD-chunked expert-contiguous grid: each XCD owns 2 experts.
template<bool WBF>
__global__ __launch_bounds__(256, 2) void k2_encode(
    const unsigned short* __restrict__ xf16,
    const unsigned short* __restrict__ wf16,
    const float* __restrict__ expert_W,
    const float* __restrict__ expert_b,
    const int* __restrict__ counts, const int* __restrict__ lists,
    const double* __restrict__ entw, unsigned short* __restrict__ fbuf)
{
    // remap: 12288 blocks; xcd = wg&7 gets contiguous 1536 = 2 experts.
    const int wg  = blockIdx.x;
    const int gw  = (wg & 7) * 1536 + (wg >> 3);
    const int e   = gw / 768;
    const int rem = gw % 768;
    const int cnt = counts[e];
    const int mbase = (rem / 12) * 128;        // mtile-major, ntile fastest
    if (mbase >= cnt) return;
    const int rows = min(128, cnt - mbase);
    const int nbase = (rem % 12) * 128;

    __shared__ char smem[65536];   // 2 buffers x (A 16KB | B 16KB)

    const int t = threadIdx.x;
    const int lane = t & 63;
    const int wid = t >> 6;
    const int wm = wid >> 1, wn = wid & 1;
    const int l15 = lane & 15, q = lane >> 4;
    const int rl = lane >> 3;          // row-within-8 for async staging
    const int cg = lane & 7;           // 16B chunk index
    const int xorc = (cg ^ rl) << 4;   // inverse-swizzled source chunk byte

    size_t asrc[4];
#pragma unroll
    for (int j = 0; j < 4; ++j) {
        const int r = (wid * 4 + j) * 8 + rl;
        const int rr = (r < rows) ? r : 0;
        const int tok = lists[e * MAXT + mbase + rr] >> 1;
        asrc[j] = (size_t)tok * (DD * 2) + xorc;
    }
    size_t bsrc[4];
#pragma unroll
    for (int j = 0; j < 4; ++j) {
        const int r = (wid * 4 + j) * 8 + rl;
        bsrc[j] = ((size_t)(e * EDD + nbase + r)) * (DD * 2) + xorc;
    }
    const int kq = t & 15, rg = t >> 4;   // !WBF B-convert map

    f32x4 acc[4][4];
#pragma unroll
    for (int a = 0; a < 4; ++a)
#pragma unroll
        for (int b = 0; b < 4; ++b)
            acc[a][b] = f32x4{0.f, 0.f, 0.f, 0.f};

    auto stageA = [&](int s, char* buf) {
#pragma unroll
        for (int j = 0; j < 4; ++j)
            async16((const char*)xf16 + asrc[j] + (size_t)s * BKBYTES,
                    buf + ((wid * 4 + j) << 10));
    };
    auto stageB_async = [&](int s, char* buf) {
#pragma unroll
        for (int j = 0; j < 4; ++j)
            async16((const char*)wf16 + bsrc[j] + (size_t)s * BKBYTES,
                    buf + 16384 + ((wid * 4 + j) << 10));
    };
    auto stageB_cvt = [&](int s, char* buf) {
#pragma unroll
        for (int j = 0; j < 8; ++j) {
            const int r = rg * 8 + j;
            const float4 bv = *reinterpret_cast<const float4*>(
                expert_W + ((size_t)e * EDD + nbase + r) * DD + s * 64 + kq * 4);
            ushort4 b4;
            b4.x = f2h_bits(bv.x); b4.y = f2h_bits(bv.y);
            b4.z = f2h_bits(bv.z); b4.w = f2h_bits(bv.w);
            *reinterpret_cast<ushort4*>(
                buf + 16384 + ((r * 128 + kq * 8) ^ ((r & 7) << 4))) = b4;
        }
    };
    auto compute = [&](char* buf) {
#pragma unroll
        for (int ks = 0; ks < 2; ++ks) {
            f16x8 ah[4], bh[4];
#pragma unroll
            for (int fm = 0; fm < 4; ++fm) {
                const int row = wm * 64 + fm * 16 + l15;
                ah[fm] = *reinterpret_cast<const f16x8*>(
                    buf + row * 128 + ((ks * 64 + q * 16) ^ ((row & 7) << 4)));
            }
#pragma unroll
            for (int fn = 0; fn < 4; ++fn) {
                const int row = wn * 64 + fn * 16 + l15;
                bh[fn] = *reinterpret_cast<const f16x8*>(
                    buf + 16384 + row * 128 + ((ks * 64 + q * 16) ^ ((row & 7) << 4)));
            }
#pragma unroll
            for (int fm = 0; fm < 4; ++fm)
#pragma unroll
                for (int fn = 0; fn < 4; ++fn)
                    acc[fm][fn] = __builtin_amdgcn_mfma_f32_16x16x32_f16(
                        ah[fm], bh[fn], acc[fm][fn], 0, 0, 0);
        }
    };

    // prologue: stage tile 0 into buffer 0
    if constexpr (WBF) {
        stageA(0, smem);
        stageB_async(0, smem);
    } else {
        stageB_cvt(0, smem);
        stageA(0, smem);
    }

    for (int s = 0; s < NSTEP; ++s) {
        char* cur = smem + ((s & 1) << 15);
        char* nxt = smem + (((s & 1) ^ 1) << 15);
        if (s + 1 < NSTEP) {
            if constexpr (WBF) {
                stageA(s + 1, nxt);
                stageB_async(s + 1, nxt);
                VMCNT8();              // retire tile s, keep tile s+1 in flight
            } else {
                stageB_cvt(s + 1, nxt);
                stageA(s + 1, nxt);
                VMCNT4();
            }
        } else {
            VMCNT0();
        }
        __syncthreads();
        compute(cur);
        __syncthreads();
    }

    // epilogue: C/D layout col=lane&15, row=(lane>>4)*4+reg; bias+relu+renorm; f16 out
#pragma unroll
    for (int fm = 0; fm < 4; ++fm) {
#pragma unroll
        for (int r = 0; r < 4; ++r) {
            const int ml = wm * 64 + fm * 16 + q * 4 + r;
            if (ml >= rows) continue;
            const int ent = lists[e * MAXT + mbase + ml];
            const float ren = (float)entw[ent];
            unsigned short* fout = fbuf + (size_t)ent * EDD + nbase;
#pragma unroll
            for (int fn = 0; fn < 4; ++fn) {
                const int nl = wn * 64 + fn * 16 + l15;
                float v = acc[fm][fn][r] + expert_b[e * EDD + nbase + nl];
                v = fmaxf(v, 0.f) * ren;
                fout[nl] = f2h_bits(v);
            }
        }
    }
}

// --------------------------- K3: per-token exact top-100 + fused decode
// 256 threads; parallel suffix-scan radix thresholds; narrow fp64 re-eval
// band (f16 encode, sigma ~0.3 ulp); expert-major + XCD-chunked dispatch.
template<int DEC16>
__global__ __launch_bounds__(256) void k3_topk_decode(
    const float* __restrict__ x, const float* __restrict__ b_dec,
    const float* __restrict__ expert_W, const float* __restrict__ expert_b,
    const int* __restrict__ eids, const double* __restrict__ entw,
    const unsigned short* __restrict__ fbuf,
    const float* __restrict__ decoder, const unsigned short* __restrict__ dec16,
    const int* __restrict__ tokord, float* __restrict__ out)
{
    const int bid = blockIdx.x;
    const int tok = tokord[(bid & 7) * (NB / 8) + (bid >> 3)];
    const int t = threadIdx.x;

    // arena overlay: [fv 6144 | hist 1024 | cidx 1024 | cval 2048] before decode;
    // red[4*768 floats = 12288] after selection (all earlier arrays dead then).
    __shared__ __align__(16) char arena[12288];
    unsigned short* fv   = (unsigned short*)arena;
    unsigned int*   hist = (unsigned int*)(arena + 6144);
    int*            cidx = (int*)(arena + 7168);
    double*         cval = (double*)(arena + 8192);
    float*          red  = (float*)arena;
    __shared__ unsigned int sc[256];
    __shared__ int hb_s, T_s, rem_s, tz_s, nsel_s, ncand_s, total_s, need_s;
    __shared__ int   sel_didx[KTOP];
    __shared__ float sel_act[KTOP];

    const unsigned int* frow = reinterpret_cast<const unsigned int*>(fbuf + (size_t)tok * 2 * EDD);
#pragma unroll
    for (int i = 0; i < 6; ++i)
        reinterpret_cast<unsigned int*>(fv)[t + 256 * i] = frow[t + 256 * i];
    if (t == 0) { tz_s = 0; nsel_s = 0; ncand_s = 0; }
    hist[t] = 0u;
    __syncthreads();

    // pass 1: top byte of f16 bits (all values >= 0)
#pragma unroll
    for (int i = 0; i < 12; ++i) {
        const unsigned int u = fv[t + 256 * i];
        if (u) atomicAdd(&hist[u >> 8], 1u);
    }
    __syncthreads();
    // parallel suffix scan: sc[v] = sum_{u>=v} hist[u]
    sc[t] = hist[t];
    __syncthreads();
    for (int off = 1; off < 256; off <<= 1) {
        const unsigned int v2 = (t < 256 - off) ? sc[t + off] : 0u;
        __syncthreads();
        sc[t] += v2;
        __syncthreads();
    }
    {
        const unsigned int above = (t == 255) ? 0u : sc[t + 1];
        if (sc[t] >= KTOP && above < KTOP) { hb_s = t; rem_s = KTOP - (int)above; }
        if (t == 0 && sc[0] < KTOP) tz_s = 1;
    }
    __syncthreads();

    if (!tz_s) {
        hist[t] = 0u;
        __syncthreads();
        const unsigned int hb = (unsigned int)hb_s;
#pragma unroll
        for (int i = 0; i < 12; ++i) {
            const unsigned int u = fv[t + 256 * i];
            if (u && (u >> 8) == hb) atomicAdd(&hist[u & 255u], 1u);
        }
        __syncthreads();
        sc[t] = hist[t];
        __syncthreads();
        for (int off = 1; off < 256; off <<= 1) {
            const unsigned int v2 = (t < 256 - off) ? sc[t + off] : 0u;
            __syncthreads();
            sc[t] += v2;
            __syncthreads();
        }
        {
            const unsigned int rem = (unsigned int)rem_s;
            const unsigned int above = (t == 255) ? 0u : sc[t + 1];
            if (sc[t] >= rem && above < rem) T_s = (hb_s << 8) | t;
        }
        __syncthreads();
    }

    if (tz_s) {
        // fewer than 100 positives: take them all (rest are exact zeros)
#pragma unroll
        for (int i = 0; i < 12; ++i) {
            const int j = t + 256 * i;
            const unsigned int u = fv[j];
            if (u) {
                const int p = atomicAdd(&nsel_s, 1);
                const int slot = (j >= EDD) ? 1 : 0;
                const int n = j - slot * EDD;
                sel_didx[p] = eids[tok * 2 + slot] * EDD + n;
                sel_act[p] = h2f_bits((unsigned short)u);
            }
        }
        __syncthreads();
        if (t == 0) total_s = nsel_s;
        __syncthreads();
    } else {
        const int T = T_s;
#pragma unroll
        for (int i = 0; i < 12; ++i) {
            const int j = t + 256 * i;
            const unsigned int u = fv[j];
            if ((int)u >= T + CONF_ULP) {
                const int p = atomicAdd(&nsel_s, 1);
                const int slot = (j >= EDD) ? 1 : 0;
                const int n = j - slot * EDD;
                sel_didx[p] = eids[tok * 2 + slot] * EDD + n;
                sel_act[p] = h2f_bits((unsigned short)u);
            } else if (u != 0u && (int)u + BAND_ULP >= T) {
                const int c = atomicAdd(&ncand_s, 1);
                if (c < CAND_MAX) cidx[c] = j;
            }
        }
        __syncthreads();

        // fp64 re-evaluation of candidates, one wave per candidate (4 waves)
        {
            const int ncand = min(ncand_s, CAND_MAX);
            const int wv = t >> 6, lane = t & 63;
            for (int c = wv; c < ncand; c += 4) {
                const int j = cidx[c];
                const int slot = (j >= EDD) ? 1 : 0;
                const int n = j - slot * EDD;
                const int ee = eids[tok * 2 + slot];
                const float* wr = expert_W + ((size_t)ee * EDD + n) * DD;
                const float* xr = x + (size_t)tok * DD;
                double d = 0.0;
#pragma unroll
                for (int jj = 0; jj < 12; ++jj) {
                    const int k = jj * 64 + lane;
                    d += ((double)xr[k] - (double)b_dec[k]) * (double)wr[k];
                }
#pragma unroll
                for (int off = 32; off > 0; off >>= 1) d += __shfl_xor(d, off);
                if (lane == 0) {
                    double z = d + (double)expert_b[ee * EDD + n];
                    if (z < 0.0) z = 0.0;
                    cval[c] = z * entw[tok * 2 + slot];
                }
            }
        }
        __syncthreads();
        if (t == 0) {
            const int ncand = min(ncand_s, CAND_MAX);
            int need = KTOP - nsel_s;
            if (need > ncand) need = ncand;
            if (need < 0) need = 0;
            need_s = need;
            total_s = nsel_s + need;
        }
        __syncthreads();

        // parallel rank-based selection among candidates (value desc, dict idx asc)
        {
            const int ncand = min(ncand_s, CAND_MAX);
            if (t < ncand) {
                const int j = cidx[t];
                const int slot = (j >= EDD) ? 1 : 0;
                const int my_didx = eids[tok * 2 + slot] * EDD + (j - slot * EDD);
                const double v = cval[t];
                int rank = 0;
                for (int i = 0; i < ncand; ++i) {
                    const int ji = cidx[i];
                    const int si = (ji >= EDD) ? 1 : 0;
                    const int di = eids[tok * 2 + si] * EDD + (ji - si * EDD);
                    const double vi = cval[i];
                    rank += (vi > v) || (vi == v && di < my_didx);
                }
                if (rank < need_s) {
                    sel_didx[nsel_s + rank] = my_didx;
                    sel_act[nsel_s + rank] = (float)v;
                }
            }
        }
        __syncthreads();
    }

    // fused decode: 4-wave k-split, 24B/lane/row, 4-deep load/FMA pipeline.
    const int total = total_s;
    const int wv = t >> 6;
    const int lane = t & 63;
    float accd[12];
#pragma unroll
    for (int i = 0; i < 12; ++i) accd[i] = 0.f;

    if (DEC16) {
        auto ldrow = [&](int k, float& a, ushort4& u0, ushort4& u1, ushort4& u2) {
            a = sel_act[k];
            const char* dr = (const char*)(dec16 + (size_t)sel_didx[k] * DD) + lane * 24;
            u0 = *reinterpret_cast<const ushort4*>(dr);
            u1 = *reinterpret_cast<const ushort4*>(dr + 8);
            u2 = *reinterpret_cast<const ushort4*>(dr + 16);
        };
        auto fmarow = [&](float a, ushort4 u0, ushort4 u1, ushort4 u2) {
            accd[0] += a * bf2f(u0.x);  accd[1]  += a * bf2f(u0.y);
            accd[2] += a * bf2f(u0.z);  accd[3]  += a * bf2f(u0.w);
            accd[4] += a * bf2f(u1.x);  accd[5]  += a * bf2f(u1.y);
            accd[6] += a * bf2f(u1.z);  accd[7]  += a * bf2f(u1.w);
            accd[8] += a * bf2f(u2.x);  accd[9]  += a * bf2f(u2.y);
            accd[10] += a * bf2f(u2.z); accd[11] += a * bf2f(u2.w);
        };
        int k = wv;
        for (; k + 12 < total; k += 16) {
            float a0, a1, a2, a3;
            ushort4 p00, p01, p02, p10, p11, p12, p20, p21, p22, p30, p31, p32;
            ldrow(k,      a0, p00, p01, p02);
            ldrow(k + 4,  a1, p10, p11, p12);
            ldrow(k + 8,  a2, p20, p21, p22);
            ldrow(k + 12, a3, p30, p31, p32);
            fmarow(a0, p00, p01, p02);
            fmarow(a1, p10, p11, p12);
            fmarow(a2, p20, p21, p22);
            fmarow(a3, p30, p31, p32);
        }
        for (; k < total; k += 4) {
            float a; ushort4 q0, q1, q2;
            ldrow(k, a, q0, q1, q2);
            fmarow(a, q0, q1, q2);
        }
    } else {
        auto body = [&](int k) {
            const float a = sel_act[k];
            const float* dr = decoder + (size_t)sel_didx[k] * DD + lane * 12;
            const float4 f0 = *reinterpret_cast<const float4*>(dr);
            const float4 f1 = *reinterpret_cast<const float4*>(dr + 4);
            const float4 f2 = *reinterpret_cast<const float4*>(dr + 8);
            accd[0] += a * f0.x;  accd[1]  += a * f0.y;
            accd[2] += a * f0.z;  accd[3]  += a * f0.w;
            accd[4] += a * f1.x;  accd[5]  += a * f1.y;
            accd[6] += a * f1.z;  accd[7]  += a * f1.w;
            accd[8] += a * f2.x;  accd[9]  += a * f2.y;
            accd[10] += a * f2.z; accd[11] += a * f2.w;
        };
        int k = wv;
        for (; k + 4 < total; k += 8) { body(k); body(k + 4); }
        if (k < total) body(k);
    }

    // red overlays the arena — all reads of fv/cval are complete by here
#pragma unroll
    for (int i = 0; i < 12; ++i)
        red[wv * DD + lane * 12 + i] = accd[i];
    __syncthreads();
#pragma unroll
    for (int i = 0; i < 3; ++i) {
        const int j = t + 256 * i;
        out[(size_t)tok * DD + j] =
            red[j] + red[DD + j] + red[2 * DD + j] + red[3 * DD + j] + b_dec[j];
    }
}

// sentinel fill if workspace is too small (diagnosable: absmax ~ 12345)
__global__ void k_sentinel(float* __restrict__ out, int n) {
    int i = blockIdx.x * blockDim.x + threadIdx.x;
    if (i < n) out[i] = 12345.0f;
}

extern "C" void kernel_launch(void* const* d_in, const int* in_sizes, int n_in,
                              void* d_out, int out_size, void* d_ws, size_t ws_size,
                              hipStream_t stream)
{
    (void)in_sizes; (void)n_in;
    const float* x        = (const float*)d_in[0];
    const float* gate_W   = (const float*)d_in[1];
    const float* gate_b   = (const float*)d_in[2];
    const float* b_gate   = (const float*)d_in[3];
    const float* b_dec    = (const float*)d_in[4];
    const float* expert_W = (const float*)d_in[5];
    const float* expert_b = (const float*)d_in[6];
    const float* decoder  = (const float*)d_in[7];
    float* out = (float*)d_out;

    char* ws = (char*)d_ws;
    const size_t off_counts0 = 64;
    const size_t off_blkcnt = 256;
    const size_t off_blkoff = off_blkcnt + (size_t)NE * K1BLK * 4;
    const size_t off_rnk    = off_blkoff + (size_t)NE * K1BLK * 4;
    const size_t off_eids   = off_rnk    + (size_t)NB * 2 * 4;
    const size_t off_entw   = off_eids   + (size_t)NB * 2 * 4;
    const size_t off_lists  = off_entw   + (size_t)NB * 2 * 8;
    const size_t off_fbuf   = off_lists  + (size_t)NE * MAXT * 4;
    const size_t off_xbf    = off_fbuf   + (size_t)NB * 2 * EDD * 2;
    const size_t off_bc0    = off_xbf    + (size_t)NB * DD * 2;
    const size_t off_bo0    = off_bc0    + (size_t)NE * K1BLK * 4;
    const size_t off_rnk0   = off_bo0    + (size_t)NE * K1BLK * 4;
    const size_t off_tokord = off_rnk0   + (size_t)NB * 4;
    const size_t base_end   = off_tokord + (size_t)NB * 4;           // ~64.4 MB
    const size_t WSZ        = (size_t)NE * EDD * DD * 2;             // 37.75 MB

    if (ws_size < base_end) {
        k_sentinel<<<(out_size + 255) / 256, 256, 0, stream>>>(out, out_size);
        return;
    }
    size_t off = base_end;
    const bool have_w = (ws_size >= off + WSZ);
    unsigned short* wf16 = have_w ? (unsigned short*)(ws + off) : nullptr;
    if (have_w) off += WSZ;
    const bool have_d = (ws_size >= off + WSZ);
    unsigned short* dec16v = have_d ? (unsigned short*)(ws + off) : nullptr;

    int*            counts  = (int*)ws;
    int*            counts0 = (int*)(ws + off_counts0);
    int*            blk_cnt = (int*)(ws + off_blkcnt);
    int*            blk_off = (int*)(ws + off_blkoff);
    int*            rnk     = (int*)(ws + off_rnk);
    int*            eids    = (int*)(ws + off_eids);
    double*         entw    = (double*)(ws + off_entw);
    int*            lists   = (int*)(ws + off_lists);
    unsigned short* fbuf    = (unsigned short*)(ws + off_fbuf);
    unsigned short* xf16    = (unsigned short*)(ws + off_xbf);
    int*            blk_cnt0= (int*)(ws + off_bc0);
    int*            blk_off0= (int*)(ws + off_bo0);
    int*            rnk0    = (int*)(ws + off_rnk0);
    int*            tokord  = (int*)(ws + off_tokord);

    hipMemsetAsync(counts, 0, 128, stream);

    const int n4blocks = (NE * EDD * DD / 4) / 256;   // 18432
    if (have_w)
        k0_cvt_f16<<<n4blocks, 256, 0, stream>>>(expert_W, wf16);
    if (have_d)
        k0_cvt_bf<<<n4blocks, 256, 0, stream>>>(decoder, dec16v);

    k1_gate<<<K1BLK, 256, 0, stream>>>(x, gate_W, gate_b, b_gate, b_dec, xf16,
                                       eids, entw, rnk, blk_cnt, rnk0, blk_cnt0);
    k1_scan<<<2 * NE, 256, 0, stream>>>(blk_cnt, blk_off, counts,
                                        blk_cnt0, blk_off0, counts0);
    k1_scatter<<<NB * 2 / 256, 256, 0, stream>>>(eids, rnk, blk_off, lists,
                                                 rnk0, blk_off0, counts0, tokord);

    if (have_w)
        k2_encode<true><<<12288, 256, 0, stream>>>(xf16, wf16, expert_W, expert_b,
                                                   counts, lists, entw, fbuf);
    else
        k2_encode<false><<<12288, 256, 0, stream>>>(xf16, wf16, expert_W, expert_b,
                                                    counts, lists, entw, fbuf);

    if (have_d)
        k3_topk_decode<1><<<NB, 256, 0, stream>>>(x, b_dec, expert_W, expert_b, eids,
                                                  entw, fbuf, decoder, dec16v, tokord, out);
    else
        k3_topk_decode<0><<<NB, 256, 0, stream>>>(x, b_dec, expert_W, expert_b, eids,
                                                  entw, fbuf, decoder, dec16v, tokord, out);
}

// Round 11
// 296.464 us; speedup vs baseline: 1.4894x; 1.0501x over previous
//
#include <hip/hip_runtime.h>
#include <hip/hip_fp16.h>
#include <cstdint>
#include <cstddef>

#define NB    8192
#define DD    768
#define NE    16
#define NPAIR 256
#define EDD   1536
#define KTOP  100
#define MAXT  8192
#define CAND_MAX 256
#define K1BLK 2048
#define NSTEP 12
#define BKBYTES 128      // 64 k * 2B
#define CONF_ULP 6
#define BAND_ULP 5

typedef __attribute__((ext_vector_type(4))) float f32x4;
typedef __attribute__((ext_vector_type(8))) _Float16 f16x8;

#define VMCNT8() asm volatile("s_waitcnt vmcnt(8)" ::: "memory")
#define VMCNT4() asm volatile("s_waitcnt vmcnt(4)" ::: "memory")
#define VMCNT0() asm volatile("s_waitcnt vmcnt(0)" ::: "memory")

__device__ __forceinline__ unsigned short f2bf(float v) {
    unsigned int u = __float_as_uint(v);
    u += 0x7FFFu + ((u >> 16) & 1u);   // RNE to bf16
    return (unsigned short)(u >> 16);
}
__device__ __forceinline__ float bf2f(unsigned short h) {
    return __uint_as_float(((unsigned int)h) << 16);
}
__device__ __forceinline__ unsigned short f2h_bits(float v) {
    return __half_as_ushort(__float2half(v));
}
__device__ __forceinline__ float h2f_bits(unsigned short b) {
    return __half2float(__ushort_as_half(b));
}
__device__ __forceinline__ void async16(const void* g, void* l) {
    __builtin_amdgcn_global_load_lds(
        (const __attribute__((address_space(1))) unsigned int*)g,
        (__attribute__((address_space(3))) unsigned int*)l, 16, 0, 0);
}

// ---------------------------------------------------------------- K0: converts
__global__ __launch_bounds__(256) void k0_cvt_bf(
    const float* __restrict__ src, unsigned short* __restrict__ dst)
{
    const int i = blockIdx.x * 256 + threadIdx.x;
    const float4 v = reinterpret_cast<const float4*>(src)[i];
    ushort4 h;
    h.x = f2bf(v.x); h.y = f2bf(v.y); h.z = f2bf(v.z); h.w = f2bf(v.w);
    reinterpret_cast<ushort4*>(dst)[i] = h;
}

__global__ __launch_bounds__(256) void k0_cvt_f16(
    const float* __restrict__ src, unsigned short* __restrict__ dst)
{
    const int i = blockIdx.x * 256 + threadIdx.x;
    const float4 v = reinterpret_cast<const float4*>(src)[i];
    ushort4 h;
    h.x = f2h_bits(v.x); h.y = f2h_bits(v.y); h.z = f2h_bits(v.z); h.w = f2h_bits(v.w);
    reinterpret_cast<ushort4*>(dst)[i] = h;
}

// ---------------------------------------------------------------- K1a: gate (+ fused xf16 emit)
// Token-order keyed by (e0,e1) PAIR (primary-major) for decode L2 locality.
__global__ __launch_bounds__(256) void k1_gate(
    const float* __restrict__ x, const float* __restrict__ gate_W,
    const float* __restrict__ gate_b, const float* __restrict__ b_gate,
    const float* __restrict__ b_dec, unsigned short* __restrict__ xf16,
    int* __restrict__ eids, double* __restrict__ entw,
    int* __restrict__ rnk, int* __restrict__ blk_cnt,
    int* __restrict__ rnk0, unsigned char* __restrict__ blk_cntp)
{
    __shared__ int cnt[NE];
    __shared__ int cntp[NPAIR];
    const int wid  = threadIdx.x >> 6;
    const int lane = threadIdx.x & 63;
    const int blk  = blockIdx.x;
    const int tok  = blk * 4 + wid;

    if (threadIdx.x < NE) cnt[threadIdx.x] = 0;
    cntp[threadIdx.x] = 0;
    __syncthreads();

    double xv[12];
#pragma unroll
    for (int j = 0; j < 12; ++j) {
        const int k = j * 64 + lane;
        const float xr = x[(size_t)tok * DD + k];
        xv[j] = (double)xr - (double)b_gate[k];
        xf16[(size_t)tok * DD + k] = f2h_bits(xr - b_dec[k]);   // fused prep_x (f16)
    }

    double myLogit = -1.0e300;
    for (int e = 0; e < NE; ++e) {
        double d = 0.0;
#pragma unroll
        for (int j = 0; j < 12; ++j)
            d += xv[j] * (double)gate_W[e * DD + j * 64 + lane];
#pragma unroll
        for (int off = 32; off > 0; off >>= 1)
            d += __shfl_xor(d, off);
        if (lane == e) myLogit = d + (double)gate_b[e];
    }

    double m = myLogit;
#pragma unroll
    for (int off = 8; off > 0; off >>= 1) {
        double o = __shfl_xor(m, off); m = (o > m) ? o : m;
    }
    double p = exp(myLogit - m);
    double ssum = p;
#pragma unroll
    for (int off = 8; off > 0; off >>= 1) ssum += __shfl_xor(ssum, off);
    const double score = p / ssum;

    const bool lt16 = (lane < NE);
    double m1 = score;
#pragma unroll
    for (int off = 8; off > 0; off >>= 1) {
        double o = __shfl_xor(m1, off); m1 = (o > m1) ? o : m1;
    }
    unsigned long long b0 = __ballot(lt16 && (score == m1));
    const int i0 = __ffsll(b0) - 1;
    double sc2 = (lane == i0) ? -1.0 : score;
    double m2 = sc2;
#pragma unroll
    for (int off = 8; off > 0; off >>= 1) {
        double o = __shfl_xor(m2, off); m2 = (o > m2) ? o : m2;
    }
    unsigned long long b1 = __ballot(lt16 && (sc2 == m2));
    const int i1 = __ffsll(b1) - 1;

    if (lane == 0) {
        const double w0 = 1.0 / (1.0 + exp(m2 - m1));
        const double w1 = 1.0 - w0;
        eids[tok * 2 + 0] = i0;
        eids[tok * 2 + 1] = i1;
        entw[tok * 2 + 0] = w0;
        entw[tok * 2 + 1] = w1;
        rnk[tok * 2 + 0] = atomicAdd(&cnt[i0], 1);
        rnk[tok * 2 + 1] = atomicAdd(&cnt[i1], 1);
        rnk0[tok] = atomicAdd(&cntp[(i0 << 4) | i1], 1);
    }
    __syncthreads();
    if (threadIdx.x < NE)
        blk_cnt[threadIdx.x * K1BLK + blk] = cnt[threadIdx.x];
    blk_cntp[(size_t)threadIdx.x * K1BLK + blk] = (unsigned char)cntp[threadIdx.x];
}

// ------------------------------------------- K1b: scan of the 16 entry lists
__global__ __launch_bounds__(256) void k1_scan(
    const int* __restrict__ bc, int* __restrict__ bo, int* __restrict__ counts)
{
    __shared__ int tsum[256];
    const int e = blockIdx.x;
    const int t = threadIdx.x;
    int loc[8]; int s = 0;
#pragma unroll
    for (int i = 0; i < 8; ++i) { loc[i] = s; s += bc[e * K1BLK + t * 8 + i]; }
    tsum[t] = s;
    __syncthreads();
    for (int off = 1; off < 256; off <<= 1) {
        const int u = (t >= off) ? tsum[t - off] : 0;
        __syncthreads();
        tsum[t] += u;
        __syncthreads();
    }
    const int excl = tsum[t] - s;
#pragma unroll
    for (int i = 0; i < 8; ++i) bo[e * K1BLK + t * 8 + i] = excl + loc[i];
    if (t == 255) counts[e] = tsum[255];
}

// ------------------------------------------- K1b': scan of the 256 pair lists (u8 -> u16)
__global__ __launch_bounds__(256) void k1_scanp(
    const unsigned char* __restrict__ bcp, unsigned short* __restrict__ bop,
    int* __restrict__ countsp)
{
    __shared__ int tsum[256];
    const int pp = blockIdx.x;
    const int t = threadIdx.x;
    int loc[8]; int s = 0;
#pragma unroll
    for (int i = 0; i < 8; ++i) { loc[i] = s; s += (int)bcp[(size_t)pp * K1BLK + t * 8 + i]; }
    tsum[t] = s;
    __syncthreads();
    for (int off = 1; off < 256; off <<= 1) {
        const int u = (t >= off) ? tsum[t - off] : 0;
        __syncthreads();
        tsum[t] += u;
        __syncthreads();
    }
    const int excl = tsum[t] - s;
#pragma unroll
    for (int i = 0; i < 8; ++i)
        bop[(size_t)pp * K1BLK + t * 8 + i] = (unsigned short)(excl + loc[i]);
    if (t == 255) countsp[pp] = tsum[255];
}

// ------------------------------------------- K1b'': pair base offsets (exclusive scan)
__global__ __launch_bounds__(256) void k1_base(
    const int* __restrict__ countsp, int* __restrict__ basep)
{
    __shared__ int ts[256];
    const int t = threadIdx.x;
    const int v = countsp[t];
    ts[t] = v;
    __syncthreads();
    for (int off = 1; off < 256; off <<= 1) {
        const int u = (t >= off) ? ts[t - off] : 0;
        __syncthreads();
        ts[t] += u;
        __syncthreads();
    }
    basep[t] = ts[t] - v;
}

// ---------------------------------------------------------------- K1c: scatter
__global__ __launch_bounds__(256) void k1_scatter(
    const int* __restrict__ eids, const int* __restrict__ rnk,
    const int* __restrict__ blk_off, int* __restrict__ lists,
    const int* __restrict__ rnk0, const unsigned short* __restrict__ bop,
    const int* __restrict__ basep, int* __restrict__ tokord)
{
    const int i = blockIdx.x * 256 + threadIdx.x;   // 16384 entries
    const int e = eids[i];
    const int blk = i >> 3;
    lists[e * MAXT + blk_off[e * K1BLK + blk] + rnk[i]] = i;
    if (!(i & 1)) {
        const int tok = i >> 1;
        const int pr = (e << 4) | eids[i | 1];
        tokord[basep[pr] + (int)bop[(size_t)pr * K1BLK + blk] + rnk0[tok]] = tok;
    }
}

// ------------------------------------------------- K2: grouped expert GEMM
// pure-f16, double-buffered LDS, all-async staging, counted vmcnt (T3+T4).
// XCD-chunked expert-contiguous grid: each XCD owns 2 experts.
template<bool WBF>
__global__ __launch_bounds__(256, 2) void k2_encode(
    const unsigned short* __restrict__ xf16,
    const unsigned short* __restrict__ wf16,
    const float* __restrict__ expert_W,
    const float* __restrict__ expert_b,
    const int* __restrict__ counts, const int* __restrict__ lists,
    const double* __restrict__ entw, unsigned short* __restrict__ fbuf)
{
    // remap: 12288 blocks; xcd = wg&7 gets contiguous 1536 = 2 experts.
    const int wg  = blockIdx.x;
    const int gw  = (wg & 7) * 1536 + (wg >> 3);
    const int e   = gw / 768;
    const int rem = gw % 768;
    const int cnt = counts[e];
    const int mbase = (rem / 12) * 128;        // mtile-major, ntile fastest
    if (mbase >= cnt) return;
    const int rows = min(128, cnt - mbase);
    const int nbase = (rem % 12) * 128;

    __shared__ char smem[65536];   // 2 buffers x (A 16KB | B 16KB)

    const int t = threadIdx.x;
    const int lane = t & 63;
    const int wid = t >> 6;
    const int wm = wid >> 1, wn = wid & 1;
    const int l15 = lane & 15, q = lane >> 4;
    const int rl = lane >> 3;          // row-within-8 for async staging
    const int cg = lane & 7;           // 16B chunk index
    const int xorc = (cg ^ rl) << 4;   // inverse-swizzled source chunk byte

    size_t asrc[4];
#pragma unroll
    for (int j = 0; j < 4; ++j) {
        const int r = (wid * 4 + j) * 8 + rl;
        const int rr = (r < rows) ? r : 0;
        const int tok = lists[e * MAXT + mbase + rr] >> 1;
        asrc[j] = (size_t)tok * (DD * 2) + xorc;
    }
    size_t bsrc[4];
#pragma unroll
    for (int j = 0; j < 4; ++j) {
        const int r = (wid * 4 + j) * 8 + rl;
        bsrc[j] = ((size_t)(e * EDD + nbase + r)) * (DD * 2) + xorc;
    }
    const int kq = t & 15, rg = t >> 4;   // !WBF B-convert map

    f32x4 acc[4][4];
#pragma unroll
    for (int a = 0; a < 4; ++a)
#pragma unroll
        for (int b = 0; b < 4; ++b)
            acc[a][b] = f32x4{0.f, 0.f, 0.f, 0.f};

    auto stageA = [&](int s, char* buf) {
#pragma unroll
        for (int j = 0; j < 4; ++j)
            async16((const char*)xf16 + asrc[j] + (size_t)s * BKBYTES,
                    buf + ((wid * 4 + j) << 10));
    };
    auto stageB_async = [&](int s, char* buf) {
#pragma unroll
        for (int j = 0; j < 4; ++j)
            async16((const char*)wf16 + bsrc[j] + (size_t)s * BKBYTES,
                    buf + 16384 + ((wid * 4 + j) << 10));
    };
    auto stageB_cvt = [&](int s, char* buf) {
#pragma unroll
        for (int j = 0; j < 8; ++j) {
            const int r = rg * 8 + j;
            const float4 bv = *reinterpret_cast<const float4*>(
                expert_W + ((size_t)e * EDD + nbase + r) * DD + s * 64 + kq * 4);
            ushort4 b4;
            b4.x = f2h_bits(bv.x); b4.y = f2h_bits(bv.y);
            b4.z = f2h_bits(bv.z); b4.w = f2h_bits(bv.w);
            *reinterpret_cast<ushort4*>(
                buf + 16384 + ((r * 128 + kq * 8) ^ ((r & 7) << 4))) = b4;
        }
    };
    auto compute = [&](char* buf) {
#pragma unroll
        for (int ks = 0; ks < 2; ++ks) {
            f16x8 ah[4], bh[4];
#pragma unroll
            for (int fm = 0; fm < 4; ++fm) {
                const int row = wm * 64 + fm * 16 + l15;
                ah[fm] = *reinterpret_cast<const f16x8*>(
                    buf + row * 128 + ((ks * 64 + q * 16) ^ ((row & 7) << 4)));
            }
#pragma unroll
            for (int fn = 0; fn < 4; ++fn) {
                const int row = wn * 64 + fn * 16 + l15;
                bh[fn] = *reinterpret_cast<const f16x8*>(
                    buf + 16384 + row * 128 + ((ks * 64 + q * 16) ^ ((row & 7) << 4)));
            }
#pragma unroll
            for (int fm = 0; fm < 4; ++fm)
#pragma unroll
                for (int fn = 0; fn < 4; ++fn)
                    acc[fm][fn] = __builtin_amdgcn_mfma_f32_16x16x32_f16(
                        ah[fm], bh[fn], acc[fm][fn], 0, 0, 0);
        }
    };

    // prologue: stage tile 0 into buffer 0
    if constexpr (WBF) {
        stageA(0, smem);
        stageB_async(0, smem);
    } else {
        stageB_cvt(0, smem);
        stageA(0, smem);
    }

    for (int s = 0; s < NSTEP; ++s) {
        char* cur = smem + ((s & 1) << 15);
        char* nxt = smem + (((s & 1) ^ 1) << 15);
        if (s + 1 < NSTEP) {
            if constexpr (WBF) {
                stageA(s + 1, nxt);
                stageB_async(s + 1, nxt);
                VMCNT8();              // retire tile s, keep tile s+1 in flight
            } else {
                stageB_cvt(s + 1, nxt);
                stageA(s + 1, nxt);
                VMCNT4();
            }
        } else {
            VMCNT0();
        }
        __syncthreads();
        compute(cur);
        __syncthreads();
    }

    // epilogue: C/D layout col=lane&15, row=(lane>>4)*4+reg; bias+relu+renorm; f16 out
#pragma unroll
    for (int fm = 0; fm < 4; ++fm) {
#pragma unroll
        for (int r = 0; r < 4; ++r) {
            const int ml = wm * 64 + fm * 16 + q * 4 + r;
            if (ml >= rows) continue;
            const int ent = lists[e * MAXT + mbase + ml];
            const float ren = (float)entw[ent];
            unsigned short* fout = fbuf + (size_t)ent * EDD + nbase;
#pragma unroll
            for (int fn = 0; fn < 4; ++fn) {
                const int nl = wn * 64 + fn * 16 + l15;
                float v = acc[fm][fn][r] + expert_b[e * EDD + nbase + nl];
                v = fmaxf(v, 0.f) * ren;
                fout[nl] = f2h_bits(v);
            }
        }
    }
}

// --------------------------- K3: per-token exact top-100 + fused decode
// 256 threads; parallel suffix-scan radix thresholds; narrow fp64 re-eval
// band (f16 encode, sigma ~0.3 ulp); (e0,e1)-pair token order + XCD chunking.
template<int DEC16>
__global__ __launch_bounds__(256) void k3_topk_decode(
    const float* __restrict__ x, const float* __restrict__ b_dec,
    const float* __restrict__ expert_W, const float* __restrict__ expert_b,
    const int* __restrict__ eids, const double* __restrict__ entw,
    const unsigned short* __restrict__ fbuf,
    const float* __restrict__ decoder, const unsigned short* __restrict__ dec16,
    const int* __restrict__ tokord, float* __restrict__ out)
{
    const int bid = blockIdx.x;
    const int tok = tokord[(bid & 7) * (NB / 8) + (bid >> 3)];
    const int t = threadIdx.x;

    // arena overlay: [fv 6144 | hist 1024 | cidx 1024 | cval 2048] before decode;
    // red[4*768 floats = 12288] after selection (all earlier arrays dead then).
    __shared__ __align__(16) char arena[12288];
    unsigned short* fv   = (unsigned short*)arena;
    unsigned int*   hist = (unsigned int*)(arena + 6144);
    int*            cidx = (int*)(arena + 7168);
    double*         cval = (double*)(arena + 8192);
    float*          red  = (float*)arena;
    __shared__ unsigned int sc[256];
    __shared__ int hb_s, T_s, rem_s, tz_s, nsel_s, ncand_s, total_s, need_s;
    __shared__ int   sel_didx[KTOP];
    __shared__ float sel_act[KTOP];

    const unsigned int* frow = reinterpret_cast<const unsigned int*>(fbuf + (size_t)tok * 2 * EDD);
#pragma unroll
    for (int i = 0; i < 6; ++i)
        reinterpret_cast<unsigned int*>(fv)[t + 256 * i] = frow[t + 256 * i];
    if (t == 0) { tz_s = 0; nsel_s = 0; ncand_s = 0; }
    hist[t] = 0u;
    __syncthreads();

    // pass 1: top byte of f16 bits (all values >= 0)
#pragma unroll
    for (int i = 0; i < 12; ++i) {
        const unsigned int u = fv[t + 256 * i];
        if (u) atomicAdd(&hist[u >> 8], 1u);
    }
    __syncthreads();
    // parallel suffix scan: sc[v] = sum_{u>=v} hist[u]
    sc[t] = hist[t];
    __syncthreads();
    for (int off = 1; off < 256; off <<= 1) {
        const unsigned int v2 = (t < 256 - off) ? sc[t + off] : 0u;
        __syncthreads();
        sc[t] += v2;
        __syncthreads();
    }
    {
        const unsigned int above = (t == 255) ? 0u : sc[t + 1];
        if (sc[t] >= KTOP && above < KTOP) { hb_s = t; rem_s = KTOP - (int)above; }
        if (t == 0 && sc[0] < KTOP) tz_s = 1;
    }
    __syncthreads();

    if (!tz_s) {
        hist[t] = 0u;
        __syncthreads();
        const unsigned int hb = (unsigned int)hb_s;
#pragma unroll
        for (int i = 0; i < 12; ++i) {
            const unsigned int u = fv[t + 256 * i];
            if (u && (u >> 8) == hb) atomicAdd(&hist[u & 255u], 1u);
        }
        __syncthreads();
        sc[t] = hist[t];
        __syncthreads();
        for (int off = 1; off < 256; off <<= 1) {
            const unsigned int v2 = (t < 256 - off) ? sc[t + off] : 0u;
            __syncthreads();
            sc[t] += v2;
            __syncthreads();
        }
        {
            const unsigned int rem = (unsigned int)rem_s;
            const unsigned int above = (t == 255) ? 0u : sc[t + 1];
            if (sc[t] >= rem && above < rem) T_s = (hb_s << 8) | t;
        }
        __syncthreads();
    }

    if (tz_s) {
        // fewer than 100 positives: take them all (rest are exact zeros)
#pragma unroll
        for (int i = 0; i < 12; ++i) {
            const int j = t + 256 * i;
            const unsigned int u = fv[j];
            if (u) {
                const int p = atomicAdd(&nsel_s, 1);
                const int slot = (j >= EDD) ? 1 : 0;
                const int n = j - slot * EDD;
                sel_didx[p] = eids[tok * 2 + slot] * EDD + n;
                sel_act[p] = h2f_bits((unsigned short)u);
            }
        }
        __syncthreads();
        if (t == 0) total_s = nsel_s;
        __syncthreads();
    } else {
        const int T = T_s;
#pragma unroll
        for (int i = 0; i < 12; ++i) {
            const int j = t + 256 * i;
            const unsigned int u = fv[j];
            if ((int)u >= T + CONF_ULP) {
                const int p = atomicAdd(&nsel_s, 1);
                const int slot = (j >= EDD) ? 1 : 0;
                const int n = j - slot * EDD;
                sel_didx[p] = eids[tok * 2 + slot] * EDD + n;
                sel_act[p] = h2f_bits((unsigned short)u);
            } else if (u != 0u && (int)u + BAND_ULP >= T) {
                const int c = atomicAdd(&ncand_s, 1);
                if (c < CAND_MAX) cidx[c] = j;
            }
        }
        __syncthreads();

        // fp64 re-evaluation of candidates, one wave per candidate (4 waves)
        {
            const int ncand = min(ncand_s, CAND_MAX);
            const int wv = t >> 6, lane = t & 63;
            for (int c = wv; c < ncand; c += 4) {
                const int j = cidx[c];
                const int slot = (j >= EDD) ? 1 : 0;
                const int n = j - slot * EDD;
                const int ee = eids[tok * 2 + slot];
                const float* wr = expert_W + ((size_t)ee * EDD + n) * DD;
                const float* xr = x + (size_t)tok * DD;
                double d = 0.0;
#pragma unroll
                for (int jj = 0; jj < 12; ++jj) {
                    const int k = jj * 64 + lane;
                    d += ((double)xr[k] - (double)b_dec[k]) * (double)wr[k];
                }
#pragma unroll
                for (int off = 32; off > 0; off >>= 1) d += __shfl_xor(d, off);
                if (lane == 0) {
                    double z = d + (double)expert_b[ee * EDD + n];
                    if (z < 0.0) z = 0.0;
                    cval[c] = z * entw[tok * 2 + slot];
                }
            }
        }
        __syncthreads();
        if (t == 0) {
            const int ncand = min(ncand_s, CAND_MAX);
            int need = KTOP - nsel_s;
            if (need > ncand) need = ncand;
            if (need < 0) need = 0;
            need_s = need;
            total_s = nsel_s + need;
        }
        __syncthreads();

        // parallel rank-based selection among candidates (value desc, dict idx asc)
        {
            const int ncand = min(ncand_s, CAND_MAX);
            if (t < ncand) {
                const int j = cidx[t];
                const int slot = (j >= EDD) ? 1 : 0;
                const int my_didx = eids[tok * 2 + slot] * EDD + (j - slot * EDD);
                const double v = cval[t];
                int rank = 0;
                for (int i = 0; i < ncand; ++i) {
                    const int ji = cidx[i];
                    const int si = (ji >= EDD) ? 1 : 0;
                    const int di = eids[tok * 2 + si] * EDD + (ji - si * EDD);
                    const double vi = cval[i];
                    rank += (vi > v) || (vi == v && di < my_didx);
                }
                if (rank < need_s) {
                    sel_didx[nsel_s + rank] = my_didx;
                    sel_act[nsel_s + rank] = (float)v;
                }
            }
        }
        __syncthreads();
    }

    // fused decode: 4-wave k-split, 24B/lane/row, 4-deep load/FMA pipeline.
    const int total = total_s;
    const int wv = t >> 6;
    const int lane = t & 63;
    float accd[12];
#pragma unroll
    for (int i = 0; i < 12; ++i) accd[i] = 0.f;

    if (DEC16) {
        auto ldrow = [&](int k, float& a, ushort4& u0, ushort4& u1, ushort4& u2) {
            a = sel_act[k];
            const char* dr = (const char*)(dec16 + (size_t)sel_didx[k] * DD) + lane * 24;
            u0 = *reinterpret_cast<const ushort4*>(dr);
            u1 = *reinterpret_cast<const ushort4*>(dr + 8);
            u2 = *reinterpret_cast<const ushort4*>(dr + 16);
        };
        auto fmarow = [&](float a, ushort4 u0, ushort4 u1, ushort4 u2) {
            accd[0] += a * bf2f(u0.x);  accd[1]  += a * bf2f(u0.y);
            accd[2] += a * bf2f(u0.z);  accd[3]  += a * bf2f(u0.w);
            accd[4] += a * bf2f(u1.x);  accd[5]  += a * bf2f(u1.y);
            accd[6] += a * bf2f(u1.z);  accd[7]  += a * bf2f(u1.w);
            accd[8] += a * bf2f(u2.x);  accd[9]  += a * bf2f(u2.y);
            accd[10] += a * bf2f(u2.z); accd[11] += a * bf2f(u2.w);
        };
        int k = wv;
        for (; k + 12 < total; k += 16) {
            float a0, a1, a2, a3;
            ushort4 p00, p01, p02, p10, p11, p12, p20, p21, p22, p30, p31, p32;
            ldrow(k,      a0, p00, p01, p02);
            ldrow(k + 4,  a1, p10, p11, p12);
            ldrow(k + 8,  a2, p20, p21, p22);
            ldrow(k + 12, a3, p30, p31, p32);
            fmarow(a0, p00, p01, p02);
            fmarow(a1, p10, p11, p12);
            fmarow(a2, p20, p21, p22);
            fmarow(a3, p30, p31, p32);
        }
        for (; k < total; k += 4) {
            float a; ushort4 q0, q1, q2;
            ldrow(k, a, q0, q1, q2);
            fmarow(a, q0, q1, q2);
        }
    } else {
        auto body = [&](int k) {
            const float a = sel_act[k];
            const float* dr = decoder + (size_t)sel_didx[k] * DD + lane * 12;
            const float4 f0 = *reinterpret_cast<const float4*>(dr);
            const float4 f1 = *reinterpret_cast<const float4*>(dr + 4);
            const float4 f2 = *reinterpret_cast<const float4*>(dr + 8);
            accd[0] += a * f0.x;  accd[1]  += a * f0.y;
            accd[2] += a * f0.z;  accd[3]  += a * f0.w;
            accd[4] += a * f1.x;  accd[5]  += a * f1.y;
            accd[6] += a * f1.z;  accd[7]  += a * f1.w;
            accd[8] += a * f2.x;  accd[9]  += a * f2.y;
            accd[10] += a * f2.z; accd[11] += a * f2.w;
        };
        int k = wv;
        for (; k + 4 < total; k += 8) { body(k); body(k + 4); }
        if (k < total) body(k);
    }

    // red overlays the arena — all reads of fv/cval are complete by here
#pragma unroll
    for (int i = 0; i < 12; ++i)
        red[wv * DD + lane * 12 + i] = accd[i];
    __syncthreads();
#pragma unroll
    for (int i = 0; i < 3; ++i) {
        const int j = t + 256 * i;
        out[(size_t)tok * DD + j] =
            red[j] + red[DD + j] + red[2 * DD + j] + red[3 * DD + j] + b_dec[j];
    }
}

// sentinel fill if workspace is too small (diagnosable: absmax ~ 12345)
__global__ void k_sentinel(float* __restrict__ out, int n) {
    int i = blockIdx.x * blockDim.x + threadIdx.x;
    if (i < n) out[i] = 12345.0f;
}

extern "C" void kernel_launch(void* const* d_in, const int* in_sizes, int n_in,
                              void* d_out, int out_size, void* d_ws, size_t ws_size,
                              hipStream_t stream)
{
    (void)in_sizes; (void)n_in;
    const float* x        = (const float*)d_in[0];
    const float* gate_W   = (const float*)d_in[1];
    const float* gate_b   = (const float*)d_in[2];
    const float* b_gate   = (const float*)d_in[3];
    const float* b_dec    = (const float*)d_in[4];
    const float* expert_W = (const float*)d_in[5];
    const float* expert_b = (const float*)d_in[6];
    const float* decoder  = (const float*)d_in[7];
    float* out = (float*)d_out;

    char* ws = (char*)d_ws;
    const size_t off_countsp = 1024;
    const size_t off_basep  = 2048;
    const size_t off_blkcnt = 4096;
    const size_t off_blkoff = off_blkcnt + (size_t)NE * K1BLK * 4;
    const size_t off_rnk    = off_blkoff + (size_t)NE * K1BLK * 4;
    const size_t off_eids   = off_rnk    + (size_t)NB * 2 * 4;
    const size_t off_entw   = off_eids   + (size_t)NB * 2 * 4;
    const size_t off_lists  = off_entw   + (size_t)NB * 2 * 8;
    const size_t off_fbuf   = off_lists  + (size_t)NE * MAXT * 4;
    const size_t off_xbf    = off_fbuf   + (size_t)NB * 2 * EDD * 2;
    const size_t off_bcp    = off_xbf    + (size_t)NB * DD * 2;
    const size_t off_bop    = off_bcp    + (size_t)NPAIR * K1BLK;       // u8
    const size_t off_rnk0   = off_bop    + (size_t)NPAIR * K1BLK * 2;   // u16
    const size_t off_tokord = off_rnk0   + (size_t)NB * 4;
    const size_t base_end   = off_tokord + (size_t)NB * 4;              // ~65.6 MB
    const size_t WSZ        = (size_t)NE * EDD * DD * 2;                // 37.75 MB

    if (ws_size < base_end) {
        k_sentinel<<<(out_size + 255) / 256, 256, 0, stream>>>(out, out_size);
        return;
    }
    size_t off = base_end;
    const bool have_w = (ws_size >= off + WSZ);
    unsigned short* wf16 = have_w ? (unsigned short*)(ws + off) : nullptr;
    if (have_w) off += WSZ;
    const bool have_d = (ws_size >= off + WSZ);
    unsigned short* dec16v = have_d ? (unsigned short*)(ws + off) : nullptr;

    int*            counts  = (int*)ws;
    int*            countsp = (int*)(ws + off_countsp);
    int*            basep   = (int*)(ws + off_basep);
    int*            blk_cnt = (int*)(ws + off_blkcnt);
    int*            blk_off = (int*)(ws + off_blkoff);
    int*            rnk     = (int*)(ws + off_rnk);
    int*            eids    = (int*)(ws + off_eids);
    double*         entw    = (double*)(ws + off_entw);
    int*            lists   = (int*)(ws + off_lists);
    unsigned short* fbuf    = (unsigned short*)(ws + off_fbuf);
    unsigned short* xf16    = (unsigned short*)(ws + off_xbf);
    unsigned char*  blk_cntp= (unsigned char*)(ws + off_bcp);
    unsigned short* bop     = (unsigned short*)(ws + off_bop);
    int*            rnk0    = (int*)(ws + off_rnk0);
    int*            tokord  = (int*)(ws + off_tokord);

    const int n4blocks = (NE * EDD * DD / 4) / 256;   // 18432
    if (have_w)
        k0_cvt_f16<<<n4blocks, 256, 0, stream>>>(expert_W, wf16);
    if (have_d)
        k0_cvt_bf<<<n4blocks, 256, 0, stream>>>(decoder, dec16v);

    k1_gate<<<K1BLK, 256, 0, stream>>>(x, gate_W, gate_b, b_gate, b_dec, xf16,
                                       eids, entw, rnk, blk_cnt, rnk0, blk_cntp);
    k1_scan<<<NE, 256, 0, stream>>>(blk_cnt, blk_off, counts);
    k1_scanp<<<NPAIR, 256, 0, stream>>>(blk_cntp, bop, countsp);
    k1_base<<<1, 256, 0, stream>>>(countsp, basep);
    k1_scatter<<<NB * 2 / 256, 256, 0, stream>>>(eids, rnk, blk_off, lists,
                                                 rnk0, bop, basep, tokord);

    if (have_w)
        k2_encode<true><<<12288, 256, 0, stream>>>(xf16, wf16, expert_W, expert_b,
                                                   counts, lists, entw, fbuf);
    else
        k2_encode<false><<<12288, 256, 0, stream>>>(xf16, wf16, expert_W, expert_b,
                                                    counts, lists, entw, fbuf);

    if (have_d)
        k3_topk_decode<1><<<NB, 256, 0, stream>>>(x, b_dec, expert_W, expert_b, eids,
                                                  entw, fbuf, decoder, dec16v, tokord, out);
    else
        k3_topk_decode<0><<<NB, 256, 0, stream>>>(x, b_dec, expert_W, expert_b, eids,
                                                  entw, fbuf, decoder, dec16v, tokord, out);
}